// Round 4
// baseline (358.156 us; speedup 1.0000x reference)
//
#include <hip/hip_runtime.h>
#include <hip/hip_bf16.h>

// Problem constants (WholeBrainRateModel)
constexpr int kN   = 50000;    // nodes
constexpr int kH   = 64;       // hidden
constexpr int kB   = 2;        // batch
constexpr int kE   = 1000000;  // edges
constexpr int kObs = 128;
constexpr int kA   = 18;
constexpr int kAff = 512;
constexpr int kEff = 256;
constexpr int kNH  = kN * kH;
constexpr int kOutOff = 2 * kB * kA;  // 72 elements: mean+log_std before next_state
constexpr int kHistBlocks = (kE + 1023) / 1024;   // 977 (scatter edge chunks)
constexpr int kPackBlocks = (kNH + 2047) / 2048;  // 1563 (8 elems/thread)
constexpr int kWprepBlocks = 80;
constexpr int kXcd = 8;                   // XCD slices (bid%8 -> XCD heuristic)
constexpr int kNperX = kN / kXcd;         // 6250 nodes per slice
constexpr int kG   = 32;                  // hist groups: ONE workgroup per group
constexpr int kEg  = kE / kG;             // 31250 edges per hist group
constexpr int kScanB = (kN + 1023) / 1024;        // 49

typedef __attribute__((ext_vector_type(8))) short short8_t;  // 8 bf16 (4 VGPRs)
typedef __attribute__((ext_vector_type(4))) float f32x4_t;

// dtype-adaptive load/store (flag==1 -> float32 buffers, else bf16).
__device__ __forceinline__ float ldf(const void* p, int i, int f32) {
  if (f32) return ((const float*)p)[i];
  unsigned short u = ((const unsigned short*)p)[i];
  union { unsigned int x; float f; } v; v.x = ((unsigned int)u) << 16; return v.f;
}
__device__ __forceinline__ void stf(void* p, int i, float val, int f32) {
  if (f32) ((float*)p)[i] = val;
  else ((__hip_bfloat16*)p)[i] = __float2bfloat16(val);
}
__device__ __forceinline__ float lo16(unsigned int w) {
  union { unsigned int i; float f; } v; v.i = w << 16; return v.f;
}
__device__ __forceinline__ float hi16(unsigned int w) {
  union { unsigned int i; float f; } v; v.i = w & 0xffff0000u; return v.f;
}
__device__ __forceinline__ unsigned int f2b(float f) {  // rne bf16 bits
  union { float f; unsigned int u; } v; v.f = f;
  unsigned int r = v.u + 0x7fffu + ((v.u >> 16) & 1u);
  return r >> 16;
}
// wave-0 dtype detector (identical data in every block -> identical answer)
__device__ __forceinline__ int detect64(const unsigned short* wprobe, int t) {
  int hits = 0;
  for (int k = 0; k < 4; ++k) {
    unsigned short u = wprobe[(t * 4 + k) * 2];
    int e = (u >> 7) & 0xFF;
    if ((u & 0x7FFFu) != 0 && e >= 108 && e <= 128) hits++;
  }
  for (int off = 32; off; off >>= 1) hits += __shfl_down(hits, off);
  return (hits < 128) ? 1 : 0;  // few plausible-bf16 => f32
}

// --- fused prep: b0 = detect+flags+proj; b1..32 = hist; then wprep ----------
// Histogram: group g's region deg_g[g*kN..] is touched by exactly ONE
// workgroup, so __HIP_MEMORY_SCOPE_WORKGROUP atomics are sufficient by the
// HIP memory model (no XCD assumptions). They stay in the local L2 -> no
// per-atomic fabric (EA) write packets, which were 32 MB/launch (the round-3
// WRITE_SIZE arithmetic: 1M device atomics x 32 B + 12.8 MB pack = 44.8 MB
// vs 43.7 measured).
extern "C" __global__ void k_prep(const unsigned short* __restrict__ wprobe,
                                  const void* __restrict__ obs,
                                  const void* __restrict__ W_in,
                                  const void* __restrict__ b_in,
                                  const int* __restrict__ aff_idx,
                                  const int* __restrict__ dst,
                                  const void* __restrict__ W_msg,
                                  const void* __restrict__ W_gate,
                                  const void* __restrict__ W_cand,
                                  int* __restrict__ dflag,
                                  int* __restrict__ flags,
                                  float* __restrict__ projected,
                                  int* __restrict__ deg_g,
                                  unsigned short* __restrict__ wt) {
  int t = threadIdx.x, b = blockIdx.x;
  if (b == 0) {
    __shared__ int sflag;
    if (t < 64) { int f = detect64(wprobe, t); if (t == 0) { sflag = f; dflag[0] = f; } }
    __syncthreads();
    int f32 = sflag;
    for (int j = t; j < kAff; j += 256) flags[aff_idx[j]] = 1;
    if (t < kB * kH) {
      int bb = t >> 6, h = t & 63;
      float acc = ldf(b_in, h, f32);
      for (int o = 0; o < kObs; ++o)
        acc += ldf(obs, bb * kObs + o, f32) * ldf(W_in, o * kH + h, f32);
      projected[t] = acc;
    }
  } else if (b <= kG) {
    int g = b - 1;
    int* reg = deg_g + g * kN;      // region owned by THIS workgroup only
    int end = (g + 1) * kEg;
    for (int e = g * kEg + t; e < end; e += 256)
      __hip_atomic_fetch_add(&reg[dst[e]], 1, __ATOMIC_RELAXED,
                             __HIP_MEMORY_SCOPE_WORKGROUP);
  } else {
    __shared__ int sflag;
    if (t < 64) { int f = detect64(wprobe, t); if (t == 0) sflag = f; }
    __syncthreads();
    int f32 = sflag;
    int i = (b - 1 - kG) * 256 + t;  // 0..20479
    if (i < 4096) {
      int n = i >> 6, k = i & 63;
      wt[i] = (unsigned short)f2b(ldf(W_msg, k * 64 + n, f32));
    } else if (i < 12288) {
      int j = i - 4096; int n = j >> 7, k = j & 127;
      wt[i] = (unsigned short)f2b(ldf(W_gate, k * 64 + n, f32));
    } else if (i < 20480) {
      int j = i - 12288; int n = j >> 7, k = j & 127;
      wt[i] = (unsigned short)f2b(ldf(W_cand, k * 64 + n, f32));
    }
  }
}

// --- scan over kN node keys (deg summed across the kG group regions) --------
extern "C" __global__ void k_scan1(const int* __restrict__ deg_g,
                                   int* __restrict__ row_off,
                                   int* __restrict__ partials) {
  __shared__ int sd[256];
  int t = threadIdx.x;
  int base = blockIdx.x * 1024 + t * 4;
  int d[4];
#pragma unroll
  for (int k = 0; k < 4; ++k) {
    int idx = base + k, s = 0;
    if (idx < kN) {
#pragma unroll
      for (int r = 0; r < kG; ++r) s += deg_g[r * kN + idx];
    }
    d[k] = s;
  }
  int s4 = d[0] + d[1] + d[2] + d[3];
  sd[t] = s4;
  __syncthreads();
  for (int off = 1; off < 256; off <<= 1) {
    int v = (t >= off) ? sd[t - off] : 0;
    __syncthreads();
    sd[t] += v;
    __syncthreads();
  }
  int excl = sd[t] - s4;
  if (t == 255) partials[blockIdx.x] = sd[255];
#pragma unroll
  for (int k = 0; k < 4; ++k) {
    if (base + k < kN) row_off[base + k] = excl;
    excl += d[k];
  }
}

// scan2 folded in: each block parallel-sums partials[0..chunk) itself.
extern "C" __global__ void k_scan3(int* __restrict__ row_off,
                                   const int* __restrict__ partials,
                                   int* __restrict__ cursor) {
  __shared__ int sd[256];
  int t = threadIdx.x;
  int chunk = blockIdx.x >> 2;           // 256 keys/block, 1024 keys/chunk
  int s = 0;
  for (int j = t; j < chunk; j += 256) s += partials[j];
  sd[t] = s;
  __syncthreads();
  for (int off = 128; off; off >>= 1) {
    if (t < off) sd[t] += sd[t + off];
    __syncthreads();
  }
  int base = sd[0];
  int i = blockIdx.x * 256 + t;
  if (i < kN) {
    int v = row_off[i] + base;
    row_off[i] = v;
    cursor[i] = v;
  }
  if (blockIdx.x == 0 && t == 0) row_off[kN] = kE;
}

// --- scatter (+pack riding along): dst-range-partitioned commits ------------
// Scatter blocks (bid < 8*977): XCD slice x = bid&7, edge chunk bid>>3; only
// edges with dst in [x*6250,(x+1)*6250) are committed, so node d's sorted_src
// span + cursor line live in XCD d/6250's L2 (write locality). Cursor atomics
// stay device-scope (correct regardless of heuristic).
// Pack blocks (bid >= 8*977): state -> bf16-packed pk, pure streaming BW that
// fills the machine while scatter blocks stall on fabric atomics.
extern "C" __global__ void k_scatter(const int* __restrict__ src,
                                     const int* __restrict__ dst,
                                     int* __restrict__ cursor,
                                     int* __restrict__ sorted_src,
                                     const unsigned short* __restrict__ wprobe,
                                     const void* __restrict__ state,
                                     unsigned int* __restrict__ pack) {
  int t = threadIdx.x;
  if (blockIdx.x < kXcd * kHistBlocks) {
    int x = blockIdx.x & 7;
    int j = blockIdx.x >> 3;
    int base = j * 1024 + t;
#pragma unroll
    for (int k = 0; k < 4; ++k) {
      int e = base + k * 256;
      if (e < kE) {
        int d = dst[e];
        if (d / kNperX == x) {
          int pos = atomicAdd(&cursor[d], 1);
          sorted_src[pos] = src[e];
        }
      }
    }
  } else {
    __shared__ int sflag;
    if (t < 64) { int f = detect64(wprobe, t); if (t == 0) sflag = f; }
    __syncthreads();
    int f32 = sflag;
    int i = (blockIdx.x - kXcd * kHistBlocks) * 2048 + t * 8;  // 8 elems/thread
    if (i < kNH) {
      uint4 o0, o1;
      if (!f32) {
        // bf16 inputs: pack is a pure bit-interleave (no rounding round-trip)
        uint4 a = *(const uint4*)((const unsigned short*)state + i);
        uint4 c = *(const uint4*)((const unsigned short*)state + kNH + i);
        o0.x = (a.x & 0xffffu) | (c.x << 16);
        o0.y = (a.x >> 16)     | (c.x & 0xffff0000u);
        o0.z = (a.y & 0xffffu) | (c.y << 16);
        o0.w = (a.y >> 16)     | (c.y & 0xffff0000u);
        o1.x = (a.z & 0xffffu) | (c.z << 16);
        o1.y = (a.z >> 16)     | (c.z & 0xffff0000u);
        o1.z = (a.w & 0xffffu) | (c.w << 16);
        o1.w = (a.w >> 16)     | (c.w & 0xffff0000u);
      } else {
        const float* sf = (const float*)state;
        unsigned int w[8];
#pragma unroll
        for (int k = 0; k < 8; ++k)
          w[k] = f2b(sf[i + k]) | (f2b(sf[kNH + i + k]) << 16);
        o0 = make_uint4(w[0], w[1], w[2], w[3]);
        o1 = make_uint4(w[4], w[5], w[6], w[7]);
      }
      *(uint4*)&pack[i] = o0;
      *(uint4*)&pack[i + 4] = o1;
    }
  }
}

// --- gather: one wave per node over its contiguous edge span ----------------
// 16-lane groups: group g handles edge e+g (and e+4+g), lane loads uint4
// (16 B = 4 packed h-columns). Cross-group shfl_xor(16/32) reduce at the end.
extern "C" __global__ __launch_bounds__(256) void k_gather(
    const unsigned int* __restrict__ pack,
    const int* __restrict__ row_off,     // span = [off[n], off[n+1])
    const int* __restrict__ sorted_src,
    unsigned int* __restrict__ agg) {
  int wave = threadIdx.x >> 6, lane = threadIdx.x & 63;
  int n = blockIdx.x * 4 + wave;
  if (n >= kN) return;
  int s  = row_off[n];
  int en = row_off[n + 1];
  int g = lane >> 4, col = lane & 15;
  const uint4* pk4 = (const uint4*)pack;
  float a0x = 0.f, a0y = 0.f, a0z = 0.f, a0w = 0.f;
  float a1x = 0.f, a1y = 0.f, a1z = 0.f, a1w = 0.f;
  for (int e = s; e < en; e += 8) {
#pragma unroll
    for (int h = 0; h < 2; ++h) {
      int ee = e + h * 4 + g;
      int idx = sorted_src[min(ee, en - 1)];
      uint4 wv = pk4[idx * 16 + col];
      if (ee >= en) { wv.x = 0u; wv.y = 0u; wv.z = 0u; wv.w = 0u; }
      a0x += lo16(wv.x); a1x += hi16(wv.x);
      a0y += lo16(wv.y); a1y += hi16(wv.y);
      a0z += lo16(wv.z); a1z += hi16(wv.z);
      a0w += lo16(wv.w); a1w += hi16(wv.w);
    }
  }
  // reduce the 4 edge-groups (lanes differing in bits 4,5) onto group 0
  a0x += __shfl_xor(a0x, 16); a0x += __shfl_xor(a0x, 32);
  a0y += __shfl_xor(a0y, 16); a0y += __shfl_xor(a0y, 32);
  a0z += __shfl_xor(a0z, 16); a0z += __shfl_xor(a0z, 32);
  a0w += __shfl_xor(a0w, 16); a0w += __shfl_xor(a0w, 32);
  a1x += __shfl_xor(a1x, 16); a1x += __shfl_xor(a1x, 32);
  a1y += __shfl_xor(a1y, 16); a1y += __shfl_xor(a1y, 32);
  a1z += __shfl_xor(a1z, 16); a1z += __shfl_xor(a1z, 32);
  a1w += __shfl_xor(a1w, 16); a1w += __shfl_xor(a1w, 32);
  if (g == 0) {
    uint4 o;
    o.x = f2b(a0x) | (f2b(a1x) << 16);
    o.y = f2b(a0y) | (f2b(a1y) << 16);
    o.z = f2b(a0z) | (f2b(a1z) << 16);
    o.w = f2b(a0w) | (f2b(a1w) << 16);
    ((uint4*)agg)[n * 16 + col] = o;
  }
}

// --- update (MFMA): msg = agg@W_msg (+inject), GRU gate/cand, next_state ----
// Block: 32 nodes x 2 batches = 64 M-rows. Wave w owns rows [16w,16w+16).
// X LDS [64][136]: cols 0-63 state bf16, cols 64-127 agg -> combined.
// Staging fully vectorized from pk/agg (already bf16-packed, both batches).
// A-frag: lane holds A[m=lane&15][k=(lane>>4)*8+j]; B-frag: B[k][n=lane&15];
// C: col=lane&15, row=(lane>>4)*4+reg (verified mappings, learn_hip m89/m91).
extern "C" __global__ __launch_bounds__(256) void k_update(
    const unsigned int* __restrict__ pk,
    const unsigned short* __restrict__ wt,   // prepped bf16 Wt msg|gate|cand
    const void* __restrict__ b_gate,
    const void* __restrict__ b_cand,
    const unsigned int* __restrict__ agg,
    const int* __restrict__ flags,
    const float* __restrict__ projected,
    const int* __restrict__ dflag,
    void* __restrict__ out) {
  __shared__ uint4 lw4[2752];    // 44032 B: msg@0(72 u16/row) gate@4608 cand@13312(136/row)
  __shared__ uint4 lx4[1088];    // 17408 B
  __shared__ float sbias[128];   // gate 0-63 | cand 64-127
  __shared__ float sproj[128];
  __shared__ int   sfl[32];
  unsigned short* lwt = (unsigned short*)lw4;
  unsigned short* lx  = (unsigned short*)lx4;
  int f32 = dflag[0];
  int t = threadIdx.x;
  int nd0 = blockIdx.x * 32;

  // weights: uint4 copies (msg 512, gate 1024, cand 1024 chunks)
  const uint4* w4 = (const uint4*)wt;
  for (int i = t; i < 512; i += 256)  { int n = i >> 3, c = i & 7;  lw4[n * 9 + c] = w4[n * 8 + c]; }
  for (int i = t; i < 1024; i += 256) { int n = i >> 4, c = i & 15; lw4[576 + n * 17 + c] = w4[512 + n * 16 + c]; }
  for (int i = t; i < 1024; i += 256) { int n = i >> 4, c = i & 15; lw4[1664 + n * 17 + c] = w4[1536 + n * 16 + c]; }

  // X: uint4 loads from pk/agg, uint2 LDS writes (split batches to rows)
  const uint4* pk4 = (const uint4*)pk;
  const uint4* ag4 = (const uint4*)agg;
  for (int i = t; i < 512; i += 256) {
    int ndl = i >> 4, c4 = i & 15;
    int ndg = min(nd0 + ndl, kN - 1);
    uint4 pv = pk4[ndg * 16 + c4];
    uint4 av = ag4[ndg * 16 + c4];
    *(uint2*)&lx[(2 * ndl) * 136 + c4 * 4] =
        make_uint2((pv.x & 0xffffu) | (pv.y << 16), (pv.z & 0xffffu) | (pv.w << 16));
    *(uint2*)&lx[(2 * ndl + 1) * 136 + c4 * 4] =
        make_uint2((pv.x >> 16) | (pv.y & 0xffff0000u), (pv.z >> 16) | (pv.w & 0xffff0000u));
    *(uint2*)&lx[(2 * ndl) * 136 + 64 + c4 * 4] =
        make_uint2((av.x & 0xffffu) | (av.y << 16), (av.z & 0xffffu) | (av.w << 16));
    *(uint2*)&lx[(2 * ndl + 1) * 136 + 64 + c4 * 4] =
        make_uint2((av.x >> 16) | (av.y & 0xffff0000u), (av.z >> 16) | (av.w & 0xffff0000u));
  }
  if (t < 64) sbias[t] = ldf(b_gate, t, f32);
  else if (t < 128) sbias[t] = ldf(b_cand, t - 64, f32);
  else sproj[t - 128] = projected[t - 128];
  if (t < 32) sfl[t] = (nd0 + t < kN) ? flags[nd0 + t] : 0;
  __syncthreads();

  int w = t >> 6, lane = t & 63;
  int q = lane >> 4, l15 = lane & 15;
  int rowb = w * 16;

  // --- msg phase: C[16x64] = agg[16x64] @ W_msg[64x64] ---
  short8_t a0 = *(const short8_t*)&lx[(rowb + l15) * 136 + 64 + q * 8];
  short8_t a1 = *(const short8_t*)&lx[(rowb + l15) * 136 + 96 + q * 8];
  f32x4_t msgc[4];
#pragma unroll
  for (int ct = 0; ct < 4; ++ct) {
    f32x4_t acc = {0.f, 0.f, 0.f, 0.f};
    short8_t b0 = *(const short8_t*)&lwt[(ct * 16 + l15) * 72 + q * 8];
    short8_t b1 = *(const short8_t*)&lwt[(ct * 16 + l15) * 72 + 32 + q * 8];
    acc = __builtin_amdgcn_mfma_f32_16x16x32_bf16(a0, b0, acc, 0, 0, 0);
    acc = __builtin_amdgcn_mfma_f32_16x16x32_bf16(a1, b1, acc, 0, 0, 0);
    msgc[ct] = acc;
  }
  // combined = msg + inject -> back into X cols 64-127 (own strip rows only)
#pragma unroll
  for (int ct = 0; ct < 4; ++ct) {
    int col = ct * 16 + l15;
    float pj0 = sproj[col], pj1 = sproj[64 + col];
#pragma unroll
    for (int r = 0; r < 4; ++r) {
      int row = rowb + q * 4 + r;
      int ndl = row >> 1, b = row & 1;
      float inj = sfl[ndl] ? (b ? pj1 : pj0) : 0.f;
      lx[row * 136 + 64 + col] = (unsigned short)f2b(msgc[ct][r] + inj);
    }
  }

  // --- gate/cand phase: K=128 over [state | combined] ---
  short8_t xa[4];
#pragma unroll
  for (int ks = 0; ks < 4; ++ks)
    xa[ks] = *(const short8_t*)&lx[(rowb + l15) * 136 + ks * 32 + q * 8];
#pragma unroll
  for (int ct = 0; ct < 4; ++ct) {
    f32x4_t accg = {0.f, 0.f, 0.f, 0.f}, accc = {0.f, 0.f, 0.f, 0.f};
#pragma unroll
    for (int ks = 0; ks < 4; ++ks) {
      short8_t bg = *(const short8_t*)&lwt[4608 + (ct * 16 + l15) * 136 + ks * 32 + q * 8];
      short8_t bc = *(const short8_t*)&lwt[13312 + (ct * 16 + l15) * 136 + ks * 32 + q * 8];
      accg = __builtin_amdgcn_mfma_f32_16x16x32_bf16(xa[ks], bg, accg, 0, 0, 0);
      accc = __builtin_amdgcn_mfma_f32_16x16x32_bf16(xa[ks], bc, accc, 0, 0, 0);
    }
    int col = ct * 16 + l15;
    float bgv = sbias[col], bcv = sbias[64 + col];
#pragma unroll
    for (int rp = 0; rp < 2; ++rp) {
      int rowe = rowb + q * 4 + 2 * rp;      // even row; odd row = same node, batch1
      int nd = nd0 + (rowe >> 1);
      if (nd >= kN) continue;
      unsigned int pv = pk[nd * 64 + col];   // both batches' state, bf16
      float z0 = 1.f / (1.f + __expf(-(accg[2 * rp] + bgv)));
      float c0 = tanhf(accc[2 * rp] + bcv);
      stf(out, kOutOff + nd * 64 + col, (1.f - z0) * lo16(pv) + z0 * c0, f32);
      float z1 = 1.f / (1.f + __expf(-(accg[2 * rp + 1] + bgv)));
      float c1 = tanhf(accc[2 * rp + 1] + bcv);
      stf(out, kOutOff + kNH + nd * 64 + col, (1.f - z1) * hi16(pv) + z1 * c1, f32);
    }
  }
}

// --- readout: mean-pool efferent, tanh decode, policy heads -----------------
extern "C" __global__ void k_readout(const void* __restrict__ W_dec,
                                     const void* __restrict__ b_dec,
                                     const void* __restrict__ W_mean,
                                     const void* __restrict__ b_mean,
                                     const void* __restrict__ W_ls,
                                     const void* __restrict__ b_ls,
                                     const int* __restrict__ eff_idx,
                                     const int* __restrict__ dflag,
                                     void* __restrict__ out) {
  __shared__ float part[8][64];
  __shared__ float ro[128], dec[128];
  int f32 = dflag[0];
  int t = threadIdx.x;          // 512 threads = 8 waves
  int wv = t >> 6, lane = t & 63;
  int b = wv >> 2, g = wv & 3;  // wave -> (batch, quarter of eff list)
  float acc = 0.f;
#pragma unroll 4
  for (int i = 0; i < 64; ++i) {
    int n = eff_idx[g * 64 + i];
    acc += ldf(out, kOutOff + b * kNH + n * 64 + lane, f32);
  }
  part[wv][lane] = acc;
  __syncthreads();
  if (t < 128) {
    int bb = t >> 6, h = t & 63;
    float s = part[bb * 4 + 0][h] + part[bb * 4 + 1][h] +
              part[bb * 4 + 2][h] + part[bb * 4 + 3][h];
    ro[t] = s * (1.f / kEff);
  }
  __syncthreads();
  if (t < 128) {
    int bb = t >> 6, h = t & 63;
    float d = ldf(b_dec, h, f32);
    for (int k = 0; k < 64; ++k) d += ro[bb * 64 + k] * ldf(W_dec, k * 64 + h, f32);
    dec[t] = tanhf(d);
  }
  __syncthreads();
  if (t < kB * kA) {
    int bb = t / kA, a = t % kA;
    float m = ldf(b_mean, a, f32), l = ldf(b_ls, a, f32);
    for (int k = 0; k < 64; ++k) {
      float dv = dec[bb * 64 + k];
      m += dv * ldf(W_mean, k * kA + a, f32);
      l += dv * ldf(W_ls, k * kA + a, f32);
    }
    l = fminf(fmaxf(l, -5.f), 2.f);
    stf(out, t, m, f32);            // mean[2][18]
    stf(out, kB * kA + t, l, f32);  // log_std[2][18]
  }
}

extern "C" void kernel_launch(void* const* d_in, const int* in_sizes, int n_in,
                              void* d_out, int out_size, void* d_ws, size_t ws_size,
                              hipStream_t stream) {
  (void)in_sizes; (void)n_in; (void)out_size; (void)ws_size;
  const void* obs    = d_in[0];
  const void* state  = d_in[1];
  const void* W_in   = d_in[2];
  const void* b_in   = d_in[3];
  const void* W_msg  = d_in[4];
  const void* W_gate = d_in[5];
  const void* b_gate = d_in[6];
  const void* W_cand = d_in[7];
  const void* b_cand = d_in[8];
  const void* W_dec  = d_in[9];
  const void* b_dec  = d_in[10];
  const void* W_mean = d_in[11];
  const void* b_mean = d_in[12];
  const void* W_ls   = d_in[13];
  const void* b_ls   = d_in[14];
  const int* src = (const int*)d_in[15];
  const int* dst = (const int*)d_in[16];
  const int* aff = (const int*)d_in[17];
  const int* eff = (const int*)d_in[18];

  // workspace layout (~38 MB)
  int* wsp        = (int*)d_ws;
  int* flags      = wsp;                    // [N]     (memset 0)
  int* deg_g      = flags + kN;             // [kG*N]  (memset 0)
  int* row_off    = deg_g + kG * kN;        // [N+1] -> pad N+64
  int* cursor     = row_off + (kN + 64);    // [N]
  int* partials   = cursor + kN;            // [512]
  int* dflag      = partials + 512;         // [16]
  float* projected = (float*)(dflag + 16);           // [128]
  int* sorted_src  = (int*)(projected + 128);        // [E]
  unsigned int* pk  = (unsigned int*)(sorted_src + kE);  // [N*H]
  unsigned int* agg = pk + kNH;                          // [N*H]
  unsigned short* wt = (unsigned short*)(agg + kNH);     // [20480] bf16

  hipMemsetAsync(flags, 0, size_t((1 + kG) * kN) * sizeof(int), stream);  // flags+deg_g
  k_prep<<<1 + kG + kWprepBlocks, 256, 0, stream>>>(
      (const unsigned short*)W_cand, obs, W_in, b_in, aff, dst,
      W_msg, W_gate, W_cand, dflag, flags, projected, deg_g, wt);
  k_scan1<<<kScanB, 256, 0, stream>>>(deg_g, row_off, partials);
  k_scan3<<<(kN + 255) / 256, 256, 0, stream>>>(row_off, partials, cursor);
  k_scatter<<<kXcd * kHistBlocks + kPackBlocks, 256, 0, stream>>>(
      src, dst, cursor, sorted_src, (const unsigned short*)W_cand, state, pk);
  k_gather<<<(kN + 3) / 4, 256, 0, stream>>>(pk, row_off, sorted_src, agg);
  k_update<<<(kN + 31) / 32, 256, 0, stream>>>(pk, wt, b_gate, b_cand,
                                               agg, flags, projected, dflag, d_out);
  k_readout<<<1, 512, 0, stream>>>(W_dec, b_dec, W_mean, b_mean, W_ls, b_ls, eff,
                                   dflag, d_out);
}

// Round 5
// 345.041 us; speedup vs baseline: 1.0380x; 1.0380x over previous
//
#include <hip/hip_runtime.h>
#include <hip/hip_bf16.h>

// Problem constants (WholeBrainRateModel)
constexpr int kN   = 50000;    // nodes
constexpr int kH   = 64;       // hidden
constexpr int kB   = 2;        // batch
constexpr int kE   = 1000000;  // edges
constexpr int kObs = 128;
constexpr int kA   = 18;
constexpr int kAff = 512;
constexpr int kEff = 256;
constexpr int kNH  = kN * kH;
constexpr int kOutOff = 2 * kB * kA;  // 72 elements: mean+log_std before next_state
constexpr int kPackBlocks = (kNH + 2047) / 2048;  // 1563 (8 elems/thread)
constexpr int kWprepBlocks = 80;
constexpr int kRanges = 8;                // node ranges (bid&7 -> XCD heuristic)
constexpr int kNr  = kN / kRanges;        // 6250 nodes per range (25 KB LDS)
constexpr int kChunks = 32;               // edge chunks
constexpr int kEc  = kE / kChunks;        // 31250 edges per chunk
constexpr int kHistB = kRanges * kChunks; // 256 hist/scatter blocks
constexpr int kScanB = (kN + 1023) / 1024;        // 49

typedef __attribute__((ext_vector_type(8))) short short8_t;  // 8 bf16 (4 VGPRs)
typedef __attribute__((ext_vector_type(4))) float f32x4_t;

// dtype-adaptive load/store (flag==1 -> float32 buffers, else bf16).
__device__ __forceinline__ float ldf(const void* p, int i, int f32) {
  if (f32) return ((const float*)p)[i];
  unsigned short u = ((const unsigned short*)p)[i];
  union { unsigned int x; float f; } v; v.x = ((unsigned int)u) << 16; return v.f;
}
__device__ __forceinline__ void stf(void* p, int i, float val, int f32) {
  if (f32) ((float*)p)[i] = val;
  else ((__hip_bfloat16*)p)[i] = __float2bfloat16(val);
}
__device__ __forceinline__ float lo16(unsigned int w) {
  union { unsigned int i; float f; } v; v.i = w << 16; return v.f;
}
__device__ __forceinline__ float hi16(unsigned int w) {
  union { unsigned int i; float f; } v; v.i = w & 0xffff0000u; return v.f;
}
__device__ __forceinline__ unsigned int f2b(float f) {  // rne bf16 bits
  union { float f; unsigned int u; } v; v.f = f;
  unsigned int r = v.u + 0x7fffu + ((v.u >> 16) & 1u);
  return r >> 16;
}
// wave-0 dtype detector (identical data in every block -> identical answer)
__device__ __forceinline__ int detect64(const unsigned short* wprobe, int t) {
  int hits = 0;
  for (int k = 0; k < 4; ++k) {
    unsigned short u = wprobe[(t * 4 + k) * 2];
    int e = (u >> 7) & 0xFF;
    if ((u & 0x7FFFu) != 0 && e >= 108 && e <= 128) hits++;
  }
  for (int off = 32; off; off >>= 1) hits += __shfl_down(hits, off);
  return (hits < 128) ? 1 : 0;  // few plausible-bf16 => f32
}

// --- fused prep: b0 = detect+flags+proj; b1..256 = LDS hist; then wprep -----
// Histogram with ZERO global atomics (rounds 3/4 measured: every global
// atomic costs a ~32 B EA write packet regardless of scope/keying; 1M of
// them = ~32 MB + ~45 us). Block (r,c) LDS-counts chunk c's edges that land
// in node range r, then writes deg_c[c][r-range] with plain coalesced
// stores. 8x redundant dst reads (32 MB streaming) buy atomic-free counting.
extern "C" __global__ void k_prep(const unsigned short* __restrict__ wprobe,
                                  const void* __restrict__ obs,
                                  const void* __restrict__ W_in,
                                  const void* __restrict__ b_in,
                                  const int* __restrict__ aff_idx,
                                  const int* __restrict__ dst,
                                  const void* __restrict__ W_msg,
                                  const void* __restrict__ W_gate,
                                  const void* __restrict__ W_cand,
                                  int* __restrict__ dflag,
                                  int* __restrict__ flags,
                                  float* __restrict__ projected,
                                  int* __restrict__ deg_c,
                                  unsigned short* __restrict__ wt) {
  __shared__ int sdeg[kNr];
  int t = threadIdx.x, b = blockIdx.x;
  if (b == 0) {
    __shared__ int sflag;
    if (t < 64) { int f = detect64(wprobe, t); if (t == 0) { sflag = f; dflag[0] = f; } }
    __syncthreads();
    int f32 = sflag;
    for (int j = t; j < kAff; j += 256) flags[aff_idx[j]] = 1;
    if (t < kB * kH) {
      int bb = t >> 6, h = t & 63;
      float acc = ldf(b_in, h, f32);
      for (int o = 0; o < kObs; ++o)
        acc += ldf(obs, bb * kObs + o, f32) * ldf(W_in, o * kH + h, f32);
      projected[t] = acc;
    }
  } else if (b <= kHistB) {
    int h = b - 1, r = h & 7, c = h >> 3;
    int r0 = r * kNr;
    for (int i = t; i < kNr; i += 256) sdeg[i] = 0;
    __syncthreads();
    int end = (c + 1) * kEc;
    for (int e = c * kEc + t; e < end; e += 256) {
      unsigned rel = (unsigned)(dst[e] - r0);
      if (rel < (unsigned)kNr) atomicAdd(&sdeg[rel], 1);  // LDS atomic only
    }
    __syncthreads();
    for (int i = t; i < kNr; i += 256) deg_c[c * kN + r0 + i] = sdeg[i];
  } else {
    __shared__ int sflag;
    if (t < 64) { int f = detect64(wprobe, t); if (t == 0) sflag = f; }
    __syncthreads();
    int f32 = sflag;
    int i = (b - 1 - kHistB) * 256 + t;  // 0..20479
    if (i < 4096) {
      int n = i >> 6, k = i & 63;
      wt[i] = (unsigned short)f2b(ldf(W_msg, k * 64 + n, f32));
    } else if (i < 12288) {
      int j = i - 4096; int n = j >> 7, k = j & 127;
      wt[i] = (unsigned short)f2b(ldf(W_gate, k * 64 + n, f32));
    } else if (i < 20480) {
      int j = i - 12288; int n = j >> 7, k = j & 127;
      wt[i] = (unsigned short)f2b(ldf(W_cand, k * 64 + n, f32));
    }
  }
}

// --- scan over kN node keys (deg summed across the kChunks regions) ---------
extern "C" __global__ void k_scan1(const int* __restrict__ deg_c,
                                   int* __restrict__ row_off,
                                   int* __restrict__ partials) {
  __shared__ int sd[256];
  int t = threadIdx.x;
  int base = blockIdx.x * 1024 + t * 4;
  int d[4];
#pragma unroll
  for (int k = 0; k < 4; ++k) {
    int idx = base + k, s = 0;
    if (idx < kN) {
#pragma unroll
      for (int r = 0; r < kChunks; ++r) s += deg_c[r * kN + idx];
    }
    d[k] = s;
  }
  int s4 = d[0] + d[1] + d[2] + d[3];
  sd[t] = s4;
  __syncthreads();
  for (int off = 1; off < 256; off <<= 1) {
    int v = (t >= off) ? sd[t - off] : 0;
    __syncthreads();
    sd[t] += v;
    __syncthreads();
  }
  int excl = sd[t] - s4;
  if (t == 255) partials[blockIdx.x] = sd[255];
#pragma unroll
  for (int k = 0; k < 4; ++k) {
    if (base + k < kN) row_off[base + k] = excl;
    excl += d[k];
  }
}

// scan2 folded in; additionally transforms deg_c in place into
// chunk_base[c][n] = row_off[n] + sum_{c'<c} deg_c[c'][n]  (atomic-free
// scatter positions). Each node column is owned by exactly one thread.
extern "C" __global__ void k_scan3(int* __restrict__ row_off,
                                   const int* __restrict__ partials,
                                   int* __restrict__ deg_c) {
  __shared__ int sd[256];
  int t = threadIdx.x;
  int chunk = blockIdx.x >> 2;           // 256 keys/block, 1024 keys/chunk
  int s = 0;
  for (int j = t; j < chunk; j += 256) s += partials[j];
  sd[t] = s;
  __syncthreads();
  for (int off = 128; off; off >>= 1) {
    if (t < off) sd[t] += sd[t + off];
    __syncthreads();
  }
  int base = sd[0];
  int i = blockIdx.x * 256 + t;
  if (i < kN) {
    int v = row_off[i] + base;
    row_off[i] = v;
    int run = v;
#pragma unroll 4
    for (int c = 0; c < kChunks; ++c) {
      int d = deg_c[c * kN + i];
      deg_c[c * kN + i] = run;   // in-place: deg -> chunk_base
      run += d;
    }
  }
  if (blockIdx.x == 0 && t == 0) row_off[kN] = kE;
}

// --- scatter (+pack riding along): ZERO global atomics ----------------------
// Block (r,c): load range r's chunk_base slice into an LDS cursor, then for
// chunk c's in-range edges take slots via LDS atomicAdd and store. Slots are
// disjoint across chunks by construction (chunk_base prefix). bid&7 = r keeps
// each range's ~500 KB sorted_src window written by one XCD (L2 locality).
// Pack blocks (bid >= 256): state -> bf16-packed pk, streaming BW filler.
extern "C" __global__ void k_scatter(const int* __restrict__ src,
                                     const int* __restrict__ dst,
                                     const int* __restrict__ chunk_base,
                                     int* __restrict__ sorted_src,
                                     const unsigned short* __restrict__ wprobe,
                                     const void* __restrict__ state,
                                     unsigned int* __restrict__ pack) {
  __shared__ int scur[kNr];
  int t = threadIdx.x;
  if (blockIdx.x < kHistB) {
    int r = blockIdx.x & 7, c = blockIdx.x >> 3;
    int r0 = r * kNr;
    for (int i = t; i < kNr; i += 256) scur[i] = chunk_base[c * kN + r0 + i];
    __syncthreads();
    int end = (c + 1) * kEc;
    for (int e = c * kEc + t; e < end; e += 256) {
      unsigned rel = (unsigned)(dst[e] - r0);
      if (rel < (unsigned)kNr) {
        int pos = atomicAdd(&scur[rel], 1);   // LDS atomic only
        sorted_src[pos] = src[e];
      }
    }
  } else {
    __shared__ int sflag;
    if (t < 64) { int f = detect64(wprobe, t); if (t == 0) sflag = f; }
    __syncthreads();
    int f32 = sflag;
    int i = (blockIdx.x - kHistB) * 2048 + t * 8;  // 8 elems/thread
    if (i < kNH) {
      uint4 o0, o1;
      if (!f32) {
        // bf16 inputs: pack is a pure bit-interleave (no rounding round-trip)
        uint4 a = *(const uint4*)((const unsigned short*)state + i);
        uint4 c4 = *(const uint4*)((const unsigned short*)state + kNH + i);
        o0.x = (a.x & 0xffffu) | (c4.x << 16);
        o0.y = (a.x >> 16)     | (c4.x & 0xffff0000u);
        o0.z = (a.y & 0xffffu) | (c4.y << 16);
        o0.w = (a.y >> 16)     | (c4.y & 0xffff0000u);
        o1.x = (a.z & 0xffffu) | (c4.z << 16);
        o1.y = (a.z >> 16)     | (c4.z & 0xffff0000u);
        o1.z = (a.w & 0xffffu) | (c4.w << 16);
        o1.w = (a.w >> 16)     | (c4.w & 0xffff0000u);
      } else {
        const float* sf = (const float*)state;
        unsigned int w[8];
#pragma unroll
        for (int k = 0; k < 8; ++k)
          w[k] = f2b(sf[i + k]) | (f2b(sf[kNH + i + k]) << 16);
        o0 = make_uint4(w[0], w[1], w[2], w[3]);
        o1 = make_uint4(w[4], w[5], w[6], w[7]);
      }
      *(uint4*)&pack[i] = o0;
      *(uint4*)&pack[i + 4] = o1;
    }
  }
}

// --- gather: one wave per node over its contiguous edge span ----------------
// 16-lane groups: group g handles edge e+g (and e+4+g), lane loads uint4
// (16 B = 4 packed h-columns). Cross-group shfl_xor(16/32) reduce at the end.
extern "C" __global__ __launch_bounds__(256) void k_gather(
    const unsigned int* __restrict__ pack,
    const int* __restrict__ row_off,     // span = [off[n], off[n+1])
    const int* __restrict__ sorted_src,
    unsigned int* __restrict__ agg) {
  int wave = threadIdx.x >> 6, lane = threadIdx.x & 63;
  int n = blockIdx.x * 4 + wave;
  if (n >= kN) return;
  int s  = row_off[n];
  int en = row_off[n + 1];
  int g = lane >> 4, col = lane & 15;
  const uint4* pk4 = (const uint4*)pack;
  float a0x = 0.f, a0y = 0.f, a0z = 0.f, a0w = 0.f;
  float a1x = 0.f, a1y = 0.f, a1z = 0.f, a1w = 0.f;
  for (int e = s; e < en; e += 8) {
#pragma unroll
    for (int h = 0; h < 2; ++h) {
      int ee = e + h * 4 + g;
      int idx = sorted_src[min(ee, en - 1)];
      uint4 wv = pk4[idx * 16 + col];
      if (ee >= en) { wv.x = 0u; wv.y = 0u; wv.z = 0u; wv.w = 0u; }
      a0x += lo16(wv.x); a1x += hi16(wv.x);
      a0y += lo16(wv.y); a1y += hi16(wv.y);
      a0z += lo16(wv.z); a1z += hi16(wv.z);
      a0w += lo16(wv.w); a1w += hi16(wv.w);
    }
  }
  // reduce the 4 edge-groups (lanes differing in bits 4,5) onto group 0
  a0x += __shfl_xor(a0x, 16); a0x += __shfl_xor(a0x, 32);
  a0y += __shfl_xor(a0y, 16); a0y += __shfl_xor(a0y, 32);
  a0z += __shfl_xor(a0z, 16); a0z += __shfl_xor(a0z, 32);
  a0w += __shfl_xor(a0w, 16); a0w += __shfl_xor(a0w, 32);
  a1x += __shfl_xor(a1x, 16); a1x += __shfl_xor(a1x, 32);
  a1y += __shfl_xor(a1y, 16); a1y += __shfl_xor(a1y, 32);
  a1z += __shfl_xor(a1z, 16); a1z += __shfl_xor(a1z, 32);
  a1w += __shfl_xor(a1w, 16); a1w += __shfl_xor(a1w, 32);
  if (g == 0) {
    uint4 o;
    o.x = f2b(a0x) | (f2b(a1x) << 16);
    o.y = f2b(a0y) | (f2b(a1y) << 16);
    o.z = f2b(a0z) | (f2b(a1z) << 16);
    o.w = f2b(a0w) | (f2b(a1w) << 16);
    ((uint4*)agg)[n * 16 + col] = o;
  }
}

// --- update (MFMA): msg = agg@W_msg (+inject), GRU gate/cand, next_state ----
// Block: 32 nodes x 2 batches = 64 M-rows. Wave w owns rows [16w,16w+16).
// X LDS [64][136]: cols 0-63 state bf16, cols 64-127 agg -> combined.
// Staging fully vectorized from pk/agg (already bf16-packed, both batches).
// A-frag: lane holds A[m=lane&15][k=(lane>>4)*8+j]; B-frag: B[k][n=lane&15];
// C: col=lane&15, row=(lane>>4)*4+reg (verified mappings, learn_hip m89/m91).
extern "C" __global__ __launch_bounds__(256) void k_update(
    const unsigned int* __restrict__ pk,
    const unsigned short* __restrict__ wt,   // prepped bf16 Wt msg|gate|cand
    const void* __restrict__ b_gate,
    const void* __restrict__ b_cand,
    const unsigned int* __restrict__ agg,
    const int* __restrict__ flags,
    const float* __restrict__ projected,
    const int* __restrict__ dflag,
    void* __restrict__ out) {
  __shared__ uint4 lw4[2752];    // 44032 B: msg@0(72 u16/row) gate@4608 cand@13312(136/row)
  __shared__ uint4 lx4[1088];    // 17408 B
  __shared__ float sbias[128];   // gate 0-63 | cand 64-127
  __shared__ float sproj[128];
  __shared__ int   sfl[32];
  unsigned short* lwt = (unsigned short*)lw4;
  unsigned short* lx  = (unsigned short*)lx4;
  int f32 = dflag[0];
  int t = threadIdx.x;
  int nd0 = blockIdx.x * 32;

  // weights: uint4 copies (msg 512, gate 1024, cand 1024 chunks)
  const uint4* w4 = (const uint4*)wt;
  for (int i = t; i < 512; i += 256)  { int n = i >> 3, c = i & 7;  lw4[n * 9 + c] = w4[n * 8 + c]; }
  for (int i = t; i < 1024; i += 256) { int n = i >> 4, c = i & 15; lw4[576 + n * 17 + c] = w4[512 + n * 16 + c]; }
  for (int i = t; i < 1024; i += 256) { int n = i >> 4, c = i & 15; lw4[1664 + n * 17 + c] = w4[1536 + n * 16 + c]; }

  // X: uint4 loads from pk/agg, uint2 LDS writes (split batches to rows)
  const uint4* pk4 = (const uint4*)pk;
  const uint4* ag4 = (const uint4*)agg;
  for (int i = t; i < 512; i += 256) {
    int ndl = i >> 4, c4 = i & 15;
    int ndg = min(nd0 + ndl, kN - 1);
    uint4 pv = pk4[ndg * 16 + c4];
    uint4 av = ag4[ndg * 16 + c4];
    *(uint2*)&lx[(2 * ndl) * 136 + c4 * 4] =
        make_uint2((pv.x & 0xffffu) | (pv.y << 16), (pv.z & 0xffffu) | (pv.w << 16));
    *(uint2*)&lx[(2 * ndl + 1) * 136 + c4 * 4] =
        make_uint2((pv.x >> 16) | (pv.y & 0xffff0000u), (pv.z >> 16) | (pv.w & 0xffff0000u));
    *(uint2*)&lx[(2 * ndl) * 136 + 64 + c4 * 4] =
        make_uint2((av.x & 0xffffu) | (av.y << 16), (av.z & 0xffffu) | (av.w << 16));
    *(uint2*)&lx[(2 * ndl + 1) * 136 + 64 + c4 * 4] =
        make_uint2((av.x >> 16) | (av.y & 0xffff0000u), (av.z >> 16) | (av.w & 0xffff0000u));
  }
  if (t < 64) sbias[t] = ldf(b_gate, t, f32);
  else if (t < 128) sbias[t] = ldf(b_cand, t - 64, f32);
  else sproj[t - 128] = projected[t - 128];
  if (t < 32) sfl[t] = (nd0 + t < kN) ? flags[nd0 + t] : 0;
  __syncthreads();

  int w = t >> 6, lane = t & 63;
  int q = lane >> 4, l15 = lane & 15;
  int rowb = w * 16;

  // --- msg phase: C[16x64] = agg[16x64] @ W_msg[64x64] ---
  short8_t a0 = *(const short8_t*)&lx[(rowb + l15) * 136 + 64 + q * 8];
  short8_t a1 = *(const short8_t*)&lx[(rowb + l15) * 136 + 96 + q * 8];
  f32x4_t msgc[4];
#pragma unroll
  for (int ct = 0; ct < 4; ++ct) {
    f32x4_t acc = {0.f, 0.f, 0.f, 0.f};
    short8_t b0 = *(const short8_t*)&lwt[(ct * 16 + l15) * 72 + q * 8];
    short8_t b1 = *(const short8_t*)&lwt[(ct * 16 + l15) * 72 + 32 + q * 8];
    acc = __builtin_amdgcn_mfma_f32_16x16x32_bf16(a0, b0, acc, 0, 0, 0);
    acc = __builtin_amdgcn_mfma_f32_16x16x32_bf16(a1, b1, acc, 0, 0, 0);
    msgc[ct] = acc;
  }
  // combined = msg + inject -> back into X cols 64-127 (own strip rows only)
#pragma unroll
  for (int ct = 0; ct < 4; ++ct) {
    int col = ct * 16 + l15;
    float pj0 = sproj[col], pj1 = sproj[64 + col];
#pragma unroll
    for (int r = 0; r < 4; ++r) {
      int row = rowb + q * 4 + r;
      int ndl = row >> 1, b = row & 1;
      float inj = sfl[ndl] ? (b ? pj1 : pj0) : 0.f;
      lx[row * 136 + 64 + col] = (unsigned short)f2b(msgc[ct][r] + inj);
    }
  }

  // --- gate/cand phase: K=128 over [state | combined] ---
  short8_t xa[4];
#pragma unroll
  for (int ks = 0; ks < 4; ++ks)
    xa[ks] = *(const short8_t*)&lx[(rowb + l15) * 136 + ks * 32 + q * 8];
#pragma unroll
  for (int ct = 0; ct < 4; ++ct) {
    f32x4_t accg = {0.f, 0.f, 0.f, 0.f}, accc = {0.f, 0.f, 0.f, 0.f};
#pragma unroll
    for (int ks = 0; ks < 4; ++ks) {
      short8_t bg = *(const short8_t*)&lwt[4608 + (ct * 16 + l15) * 136 + ks * 32 + q * 8];
      short8_t bc = *(const short8_t*)&lwt[13312 + (ct * 16 + l15) * 136 + ks * 32 + q * 8];
      accg = __builtin_amdgcn_mfma_f32_16x16x32_bf16(xa[ks], bg, accg, 0, 0, 0);
      accc = __builtin_amdgcn_mfma_f32_16x16x32_bf16(xa[ks], bc, accc, 0, 0, 0);
    }
    int col = ct * 16 + l15;
    float bgv = sbias[col], bcv = sbias[64 + col];
#pragma unroll
    for (int rp = 0; rp < 2; ++rp) {
      int rowe = rowb + q * 4 + 2 * rp;      // even row; odd row = same node, batch1
      int nd = nd0 + (rowe >> 1);
      if (nd >= kN) continue;
      unsigned int pv = pk[nd * 64 + col];   // both batches' state, bf16
      float z0 = 1.f / (1.f + __expf(-(accg[2 * rp] + bgv)));
      float c0 = tanhf(accc[2 * rp] + bcv);
      stf(out, kOutOff + nd * 64 + col, (1.f - z0) * lo16(pv) + z0 * c0, f32);
      float z1 = 1.f / (1.f + __expf(-(accg[2 * rp + 1] + bgv)));
      float c1 = tanhf(accc[2 * rp + 1] + bcv);
      stf(out, kOutOff + kNH + nd * 64 + col, (1.f - z1) * hi16(pv) + z1 * c1, f32);
    }
  }
}

// --- readout: mean-pool efferent, tanh decode, policy heads -----------------
extern "C" __global__ void k_readout(const void* __restrict__ W_dec,
                                     const void* __restrict__ b_dec,
                                     const void* __restrict__ W_mean,
                                     const void* __restrict__ b_mean,
                                     const void* __restrict__ W_ls,
                                     const void* __restrict__ b_ls,
                                     const int* __restrict__ eff_idx,
                                     const int* __restrict__ dflag,
                                     void* __restrict__ out) {
  __shared__ float part[8][64];
  __shared__ float ro[128], dec[128];
  int f32 = dflag[0];
  int t = threadIdx.x;          // 512 threads = 8 waves
  int wv = t >> 6, lane = t & 63;
  int b = wv >> 2, g = wv & 3;  // wave -> (batch, quarter of eff list)
  float acc = 0.f;
#pragma unroll 4
  for (int i = 0; i < 64; ++i) {
    int n = eff_idx[g * 64 + i];
    acc += ldf(out, kOutOff + b * kNH + n * 64 + lane, f32);
  }
  part[wv][lane] = acc;
  __syncthreads();
  if (t < 128) {
    int bb = t >> 6, h = t & 63;
    float s = part[bb * 4 + 0][h] + part[bb * 4 + 1][h] +
              part[bb * 4 + 2][h] + part[bb * 4 + 3][h];
    ro[t] = s * (1.f / kEff);
  }
  __syncthreads();
  if (t < 128) {
    int bb = t >> 6, h = t & 63;
    float d = ldf(b_dec, h, f32);
    for (int k = 0; k < 64; ++k) d += ro[bb * 64 + k] * ldf(W_dec, k * 64 + h, f32);
    dec[t] = tanhf(d);
  }
  __syncthreads();
  if (t < kB * kA) {
    int bb = t / kA, a = t % kA;
    float m = ldf(b_mean, a, f32), l = ldf(b_ls, a, f32);
    for (int k = 0; k < 64; ++k) {
      float dv = dec[bb * 64 + k];
      m += dv * ldf(W_mean, k * kA + a, f32);
      l += dv * ldf(W_ls, k * kA + a, f32);
    }
    l = fminf(fmaxf(l, -5.f), 2.f);
    stf(out, t, m, f32);            // mean[2][18]
    stf(out, kB * kA + t, l, f32);  // log_std[2][18]
  }
}

extern "C" void kernel_launch(void* const* d_in, const int* in_sizes, int n_in,
                              void* d_out, int out_size, void* d_ws, size_t ws_size,
                              hipStream_t stream) {
  (void)in_sizes; (void)n_in; (void)out_size; (void)ws_size;
  const void* obs    = d_in[0];
  const void* state  = d_in[1];
  const void* W_in   = d_in[2];
  const void* b_in   = d_in[3];
  const void* W_msg  = d_in[4];
  const void* W_gate = d_in[5];
  const void* b_gate = d_in[6];
  const void* W_cand = d_in[7];
  const void* b_cand = d_in[8];
  const void* W_dec  = d_in[9];
  const void* b_dec  = d_in[10];
  const void* W_mean = d_in[11];
  const void* b_mean = d_in[12];
  const void* W_ls   = d_in[13];
  const void* b_ls   = d_in[14];
  const int* src = (const int*)d_in[15];
  const int* dst = (const int*)d_in[16];
  const int* aff = (const int*)d_in[17];
  const int* eff = (const int*)d_in[18];

  // workspace layout (~36 MB)
  int* wsp        = (int*)d_ws;
  int* flags      = wsp;                    // [N]     (memset 0)
  int* deg_c      = flags + kN;             // [kChunks*N]; becomes chunk_base in scan3
  int* row_off    = deg_c + kChunks * kN;   // [N+1] -> pad N+64
  int* partials   = row_off + (kN + 64);    // [512]
  int* dflag      = partials + 512;         // [16]
  float* projected = (float*)(dflag + 16);           // [128]
  int* sorted_src  = (int*)(projected + 128);        // [E]
  unsigned int* pk  = (unsigned int*)(sorted_src + kE);  // [N*H]
  unsigned int* agg = pk + kNH;                          // [N*H]
  unsigned short* wt = (unsigned short*)(agg + kNH);     // [20480] bf16

  hipMemsetAsync(flags, 0, size_t(kN) * sizeof(int), stream);  // flags only
  k_prep<<<1 + kHistB + kWprepBlocks, 256, 0, stream>>>(
      (const unsigned short*)W_cand, obs, W_in, b_in, aff, dst,
      W_msg, W_gate, W_cand, dflag, flags, projected, deg_c, wt);
  k_scan1<<<kScanB, 256, 0, stream>>>(deg_c, row_off, partials);
  k_scan3<<<(kN + 255) / 256, 256, 0, stream>>>(row_off, partials, deg_c);
  k_scatter<<<kHistB + kPackBlocks, 256, 0, stream>>>(
      src, dst, deg_c, sorted_src, (const unsigned short*)W_cand, state, pk);
  k_gather<<<(kN + 3) / 4, 256, 0, stream>>>(pk, row_off, sorted_src, agg);
  k_update<<<(kN + 31) / 32, 256, 0, stream>>>(pk, wt, b_gate, b_cand,
                                               agg, flags, projected, dflag, d_out);
  k_readout<<<1, 512, 0, stream>>>(W_dec, b_dec, W_mean, b_mean, W_ls, b_ls, eff,
                                   dflag, d_out);
}

// Round 6
// 285.484 us; speedup vs baseline: 1.2546x; 1.2086x over previous
//
#include <hip/hip_runtime.h>
#include <hip/hip_bf16.h>

// Problem constants (WholeBrainRateModel)
constexpr int kN   = 50000;    // nodes
constexpr int kH   = 64;       // hidden
constexpr int kB   = 2;        // batch
constexpr int kE   = 1000000;  // edges
constexpr int kObs = 128;
constexpr int kA   = 18;
constexpr int kAff = 512;
constexpr int kEff = 256;
constexpr int kNH  = kN * kH;
constexpr int kOutOff = 2 * kB * kA;  // 72 elements: mean+log_std before next_state
constexpr int kRanges = 8;                // node ranges (bid&7 -> XCD heuristic)
constexpr int kNr  = kN / kRanges;        // 6250 nodes per range (25 KB LDS)
constexpr int kChunks = 64;               // edge chunks
constexpr int kEc  = kE / kChunks;        // 15625 edges per chunk
constexpr int kHistB = kRanges * kChunks; // 512 hist/scatter blocks (1024 thr)
constexpr int kPackBlocks = (kNH + 8191) / 8192;  // 391 (8 elems/thread @1024)
constexpr int kWprepBlocks = 20;                  // 20480 / 1024
constexpr int kScanB = (kN + 1023) / 1024;        // 49

typedef __attribute__((ext_vector_type(8))) short short8_t;  // 8 bf16 (4 VGPRs)
typedef __attribute__((ext_vector_type(4))) float f32x4_t;

// dtype-adaptive load/store (flag==1 -> float32 buffers, else bf16).
__device__ __forceinline__ float ldf(const void* p, int i, int f32) {
  if (f32) return ((const float*)p)[i];
  unsigned short u = ((const unsigned short*)p)[i];
  union { unsigned int x; float f; } v; v.x = ((unsigned int)u) << 16; return v.f;
}
__device__ __forceinline__ void stf(void* p, int i, float val, int f32) {
  if (f32) ((float*)p)[i] = val;
  else ((__hip_bfloat16*)p)[i] = __float2bfloat16(val);
}
__device__ __forceinline__ float lo16(unsigned int w) {
  union { unsigned int i; float f; } v; v.i = w << 16; return v.f;
}
__device__ __forceinline__ float hi16(unsigned int w) {
  union { unsigned int i; float f; } v; v.i = w & 0xffff0000u; return v.f;
}
__device__ __forceinline__ unsigned int f2b(float f) {  // rne bf16 bits
  union { float f; unsigned int u; } v; v.f = f;
  unsigned int r = v.u + 0x7fffu + ((v.u >> 16) & 1u);
  return r >> 16;
}
// wave-0 dtype detector (identical data in every block -> identical answer)
__device__ __forceinline__ int detect64(const unsigned short* wprobe, int t) {
  int hits = 0;
  for (int k = 0; k < 4; ++k) {
    unsigned short u = wprobe[(t * 4 + k) * 2];
    int e = (u >> 7) & 0xFF;
    if ((u & 0x7FFFu) != 0 && e >= 108 && e <= 128) hits++;
  }
  for (int off = 32; off; off >>= 1) hits += __shfl_down(hits, off);
  return (hits < 128) ? 1 : 0;  // few plausible-bf16 => f32
}

// --- fused prep (1024 thr): b0 = detect+flags+proj; b1..512 = hist; wprep ---
// Histogram with ZERO global atomics (rounds 3/4: every global atomic costs a
// ~32 B EA write packet; 1M of them = ~32 MB + 45+ us). Round 5 lesson: the
// 256-block version was LATENCY-bound (1 blk/CU tail, 15% occupancy), so now
// 512 blocks x 1024 threads (2 blk/CU, 32 waves/CU) and 15 edge-iters/thread.
// Block (r,c) LDS-counts chunk c's edges landing in range r, then plain
// coalesced stores to deg_c[c][range r].
extern "C" __global__ __launch_bounds__(1024) void k_prep(
    const unsigned short* __restrict__ wprobe,
    const void* __restrict__ obs,
    const void* __restrict__ W_in,
    const void* __restrict__ b_in,
    const int* __restrict__ aff_idx,
    const int* __restrict__ dst,
    const void* __restrict__ W_msg,
    const void* __restrict__ W_gate,
    const void* __restrict__ W_cand,
    int* __restrict__ dflag,
    int* __restrict__ flags,
    float* __restrict__ projected,
    int* __restrict__ deg_c,
    unsigned short* __restrict__ wt) {
  __shared__ int sdeg[kNr];
  int t = threadIdx.x, b = blockIdx.x;
  if (b == 0) {
    __shared__ int sflag;
    if (t < 64) { int f = detect64(wprobe, t); if (t == 0) { sflag = f; dflag[0] = f; } }
    __syncthreads();
    int f32 = sflag;
    if (t < kAff) flags[aff_idx[t]] = 1;
    if (t < kB * kH) {
      int bb = t >> 6, h = t & 63;
      float acc = ldf(b_in, h, f32);
      for (int o = 0; o < kObs; ++o)
        acc += ldf(obs, bb * kObs + o, f32) * ldf(W_in, o * kH + h, f32);
      projected[t] = acc;
    }
  } else if (b <= kHistB) {
    int h = b - 1, r = h & 7, c = h >> 3;
    int r0 = r * kNr;
    for (int i = t; i < kNr; i += 1024) sdeg[i] = 0;
    __syncthreads();
    int end = (c + 1) * kEc;
    for (int e = c * kEc + t; e < end; e += 1024) {
      unsigned rel = (unsigned)(dst[e] - r0);
      if (rel < (unsigned)kNr) atomicAdd(&sdeg[rel], 1);  // LDS atomic only
    }
    __syncthreads();
    for (int i = t; i < kNr; i += 1024) deg_c[c * kN + r0 + i] = sdeg[i];
  } else {
    __shared__ int sflag;
    if (t < 64) { int f = detect64(wprobe, t); if (t == 0) sflag = f; }
    __syncthreads();
    int f32 = sflag;
    int i = (b - 1 - kHistB) * 1024 + t;  // 0..20479
    if (i < 4096) {
      int n = i >> 6, k = i & 63;
      wt[i] = (unsigned short)f2b(ldf(W_msg, k * 64 + n, f32));
    } else if (i < 12288) {
      int j = i - 4096; int n = j >> 7, k = j & 127;
      wt[i] = (unsigned short)f2b(ldf(W_gate, k * 64 + n, f32));
    } else if (i < 20480) {
      int j = i - 12288; int n = j >> 7, k = j & 127;
      wt[i] = (unsigned short)f2b(ldf(W_cand, k * 64 + n, f32));
    }
  }
}

// --- scan over kN node keys (deg summed across the kChunks regions) ---------
extern "C" __global__ void k_scan1(const int* __restrict__ deg_c,
                                   int* __restrict__ row_off,
                                   int* __restrict__ partials) {
  __shared__ int sd[256];
  int t = threadIdx.x;
  int base = blockIdx.x * 1024 + t * 4;
  int d[4];
#pragma unroll
  for (int k = 0; k < 4; ++k) {
    int idx = base + k, s = 0;
    if (idx < kN) {
      for (int r = 0; r < kChunks; ++r) s += deg_c[r * kN + idx];
    }
    d[k] = s;
  }
  int s4 = d[0] + d[1] + d[2] + d[3];
  sd[t] = s4;
  __syncthreads();
  for (int off = 1; off < 256; off <<= 1) {
    int v = (t >= off) ? sd[t - off] : 0;
    __syncthreads();
    sd[t] += v;
    __syncthreads();
  }
  int excl = sd[t] - s4;
  if (t == 255) partials[blockIdx.x] = sd[255];
#pragma unroll
  for (int k = 0; k < 4; ++k) {
    if (base + k < kN) row_off[base + k] = excl;
    excl += d[k];
  }
}

// scan2 folded in; additionally transforms deg_c in place into
// chunk_base[c][n] = row_off[n] + sum_{c'<c} deg_c[c'][n]  (atomic-free
// scatter positions). Each node column is owned by exactly one thread.
extern "C" __global__ void k_scan3(int* __restrict__ row_off,
                                   const int* __restrict__ partials,
                                   int* __restrict__ deg_c) {
  __shared__ int sd[256];
  int t = threadIdx.x;
  int chunk = blockIdx.x >> 2;           // 256 keys/block, 1024 keys/chunk
  int s = 0;
  for (int j = t; j < chunk; j += 256) s += partials[j];
  sd[t] = s;
  __syncthreads();
  for (int off = 128; off; off >>= 1) {
    if (t < off) sd[t] += sd[t + off];
    __syncthreads();
  }
  int base = sd[0];
  int i = blockIdx.x * 256 + t;
  if (i < kN) {
    int v = row_off[i] + base;
    row_off[i] = v;
    int run = v;
#pragma unroll 8
    for (int c = 0; c < kChunks; ++c) {
      int d = deg_c[c * kN + i];
      deg_c[c * kN + i] = run;   // in-place: deg -> chunk_base
      run += d;
    }
  }
  if (blockIdx.x == 0 && t == 0) row_off[kN] = kE;
}

// --- scatter (+pack riding along), 1024 thr: ZERO global atomics ------------
// Block (r,c): load range r's chunk_base slice into an LDS cursor, then for
// chunk c's in-range edges take slots via LDS atomicAdd and store. Slots are
// disjoint across chunks by construction (chunk_base prefix). bid&7 = r keeps
// each range's ~500 KB sorted_src window written by one XCD (L2 locality).
// Pack blocks (bid >= 512): state -> bf16-packed pk, streaming BW filler.
extern "C" __global__ __launch_bounds__(1024) void k_scatter(
    const int* __restrict__ src,
    const int* __restrict__ dst,
    const int* __restrict__ chunk_base,
    int* __restrict__ sorted_src,
    const unsigned short* __restrict__ wprobe,
    const void* __restrict__ state,
    unsigned int* __restrict__ pack) {
  __shared__ int scur[kNr];
  int t = threadIdx.x;
  if (blockIdx.x < kHistB) {
    int r = blockIdx.x & 7, c = blockIdx.x >> 3;
    int r0 = r * kNr;
    for (int i = t; i < kNr; i += 1024) scur[i] = chunk_base[c * kN + r0 + i];
    __syncthreads();
    int end = (c + 1) * kEc;
    for (int e = c * kEc + t; e < end; e += 1024) {
      unsigned rel = (unsigned)(dst[e] - r0);
      if (rel < (unsigned)kNr) {
        int pos = atomicAdd(&scur[rel], 1);   // LDS atomic only
        sorted_src[pos] = src[e];
      }
    }
  } else {
    __shared__ int sflag;
    if (t < 64) { int f = detect64(wprobe, t); if (t == 0) sflag = f; }
    __syncthreads();
    int f32 = sflag;
    int i = (blockIdx.x - kHistB) * 8192 + t * 8;  // 8 elems/thread
    if (i < kNH) {
      uint4 o0, o1;
      if (!f32) {
        // bf16 inputs: pack is a pure bit-interleave (no rounding round-trip)
        uint4 a = *(const uint4*)((const unsigned short*)state + i);
        uint4 c4 = *(const uint4*)((const unsigned short*)state + kNH + i);
        o0.x = (a.x & 0xffffu) | (c4.x << 16);
        o0.y = (a.x >> 16)     | (c4.x & 0xffff0000u);
        o0.z = (a.y & 0xffffu) | (c4.y << 16);
        o0.w = (a.y >> 16)     | (c4.y & 0xffff0000u);
        o1.x = (a.z & 0xffffu) | (c4.z << 16);
        o1.y = (a.z >> 16)     | (c4.z & 0xffff0000u);
        o1.z = (a.w & 0xffffu) | (c4.w << 16);
        o1.w = (a.w >> 16)     | (c4.w & 0xffff0000u);
      } else {
        const float* sf = (const float*)state;
        unsigned int w[8];
#pragma unroll
        for (int k = 0; k < 8; ++k)
          w[k] = f2b(sf[i + k]) | (f2b(sf[kNH + i + k]) << 16);
        o0 = make_uint4(w[0], w[1], w[2], w[3]);
        o1 = make_uint4(w[4], w[5], w[6], w[7]);
      }
      *(uint4*)&pack[i] = o0;
      *(uint4*)&pack[i + 4] = o1;
    }
  }
}

// --- gather: one wave per node over its contiguous edge span ----------------
// 16-lane groups: group g handles edge e+g (and e+4+g), lane loads uint4
// (16 B = 4 packed h-columns). Cross-group shfl_xor(16/32) reduce at the end.
extern "C" __global__ __launch_bounds__(256) void k_gather(
    const unsigned int* __restrict__ pack,
    const int* __restrict__ row_off,     // span = [off[n], off[n+1])
    const int* __restrict__ sorted_src,
    unsigned int* __restrict__ agg) {
  int wave = threadIdx.x >> 6, lane = threadIdx.x & 63;
  int n = blockIdx.x * 4 + wave;
  if (n >= kN) return;
  int s  = row_off[n];
  int en = row_off[n + 1];
  int g = lane >> 4, col = lane & 15;
  const uint4* pk4 = (const uint4*)pack;
  float a0x = 0.f, a0y = 0.f, a0z = 0.f, a0w = 0.f;
  float a1x = 0.f, a1y = 0.f, a1z = 0.f, a1w = 0.f;
  for (int e = s; e < en; e += 8) {
#pragma unroll
    for (int h = 0; h < 2; ++h) {
      int ee = e + h * 4 + g;
      int idx = sorted_src[min(ee, en - 1)];
      uint4 wv = pk4[idx * 16 + col];
      if (ee >= en) { wv.x = 0u; wv.y = 0u; wv.z = 0u; wv.w = 0u; }
      a0x += lo16(wv.x); a1x += hi16(wv.x);
      a0y += lo16(wv.y); a1y += hi16(wv.y);
      a0z += lo16(wv.z); a1z += hi16(wv.z);
      a0w += lo16(wv.w); a1w += hi16(wv.w);
    }
  }
  // reduce the 4 edge-groups (lanes differing in bits 4,5) onto group 0
  a0x += __shfl_xor(a0x, 16); a0x += __shfl_xor(a0x, 32);
  a0y += __shfl_xor(a0y, 16); a0y += __shfl_xor(a0y, 32);
  a0z += __shfl_xor(a0z, 16); a0z += __shfl_xor(a0z, 32);
  a0w += __shfl_xor(a0w, 16); a0w += __shfl_xor(a0w, 32);
  a1x += __shfl_xor(a1x, 16); a1x += __shfl_xor(a1x, 32);
  a1y += __shfl_xor(a1y, 16); a1y += __shfl_xor(a1y, 32);
  a1z += __shfl_xor(a1z, 16); a1z += __shfl_xor(a1z, 32);
  a1w += __shfl_xor(a1w, 16); a1w += __shfl_xor(a1w, 32);
  if (g == 0) {
    uint4 o;
    o.x = f2b(a0x) | (f2b(a1x) << 16);
    o.y = f2b(a0y) | (f2b(a1y) << 16);
    o.z = f2b(a0z) | (f2b(a1z) << 16);
    o.w = f2b(a0w) | (f2b(a1w) << 16);
    ((uint4*)agg)[n * 16 + col] = o;
  }
}

// --- update (MFMA): msg = agg@W_msg (+inject), GRU gate/cand, next_state ----
// Block: 32 nodes x 2 batches = 64 M-rows. Wave w owns rows [16w,16w+16).
// X LDS [64][136]: cols 0-63 state bf16, cols 64-127 agg -> combined.
// Staging fully vectorized from pk/agg (already bf16-packed, both batches).
// A-frag: lane holds A[m=lane&15][k=(lane>>4)*8+j]; B-frag: B[k][n=lane&15];
// C: col=lane&15, row=(lane>>4)*4+reg (verified mappings, learn_hip m89/m91).
extern "C" __global__ __launch_bounds__(256) void k_update(
    const unsigned int* __restrict__ pk,
    const unsigned short* __restrict__ wt,   // prepped bf16 Wt msg|gate|cand
    const void* __restrict__ b_gate,
    const void* __restrict__ b_cand,
    const unsigned int* __restrict__ agg,
    const int* __restrict__ flags,
    const float* __restrict__ projected,
    const int* __restrict__ dflag,
    void* __restrict__ out) {
  __shared__ uint4 lw4[2752];    // 44032 B: msg@0(72 u16/row) gate@4608 cand@13312(136/row)
  __shared__ uint4 lx4[1088];    // 17408 B
  __shared__ float sbias[128];   // gate 0-63 | cand 64-127
  __shared__ float sproj[128];
  __shared__ int   sfl[32];
  unsigned short* lwt = (unsigned short*)lw4;
  unsigned short* lx  = (unsigned short*)lx4;
  int f32 = dflag[0];
  int t = threadIdx.x;
  int nd0 = blockIdx.x * 32;

  // weights: uint4 copies (msg 512, gate 1024, cand 1024 chunks)
  const uint4* w4 = (const uint4*)wt;
  for (int i = t; i < 512; i += 256)  { int n = i >> 3, c = i & 7;  lw4[n * 9 + c] = w4[n * 8 + c]; }
  for (int i = t; i < 1024; i += 256) { int n = i >> 4, c = i & 15; lw4[576 + n * 17 + c] = w4[512 + n * 16 + c]; }
  for (int i = t; i < 1024; i += 256) { int n = i >> 4, c = i & 15; lw4[1664 + n * 17 + c] = w4[1536 + n * 16 + c]; }

  // X: uint4 loads from pk/agg, uint2 LDS writes (split batches to rows)
  const uint4* pk4 = (const uint4*)pk;
  const uint4* ag4 = (const uint4*)agg;
  for (int i = t; i < 512; i += 256) {
    int ndl = i >> 4, c4 = i & 15;
    int ndg = min(nd0 + ndl, kN - 1);
    uint4 pv = pk4[ndg * 16 + c4];
    uint4 av = ag4[ndg * 16 + c4];
    *(uint2*)&lx[(2 * ndl) * 136 + c4 * 4] =
        make_uint2((pv.x & 0xffffu) | (pv.y << 16), (pv.z & 0xffffu) | (pv.w << 16));
    *(uint2*)&lx[(2 * ndl + 1) * 136 + c4 * 4] =
        make_uint2((pv.x >> 16) | (pv.y & 0xffff0000u), (pv.z >> 16) | (pv.w & 0xffff0000u));
    *(uint2*)&lx[(2 * ndl) * 136 + 64 + c4 * 4] =
        make_uint2((av.x & 0xffffu) | (av.y << 16), (av.z & 0xffffu) | (av.w << 16));
    *(uint2*)&lx[(2 * ndl + 1) * 136 + 64 + c4 * 4] =
        make_uint2((av.x >> 16) | (av.y & 0xffff0000u), (av.z >> 16) | (av.w & 0xffff0000u));
  }
  if (t < 64) sbias[t] = ldf(b_gate, t, f32);
  else if (t < 128) sbias[t] = ldf(b_cand, t - 64, f32);
  else sproj[t - 128] = projected[t - 128];
  if (t < 32) sfl[t] = (nd0 + t < kN) ? flags[nd0 + t] : 0;
  __syncthreads();

  int w = t >> 6, lane = t & 63;
  int q = lane >> 4, l15 = lane & 15;
  int rowb = w * 16;

  // --- msg phase: C[16x64] = agg[16x64] @ W_msg[64x64] ---
  short8_t a0 = *(const short8_t*)&lx[(rowb + l15) * 136 + 64 + q * 8];
  short8_t a1 = *(const short8_t*)&lx[(rowb + l15) * 136 + 96 + q * 8];
  f32x4_t msgc[4];
#pragma unroll
  for (int ct = 0; ct < 4; ++ct) {
    f32x4_t acc = {0.f, 0.f, 0.f, 0.f};
    short8_t b0 = *(const short8_t*)&lwt[(ct * 16 + l15) * 72 + q * 8];
    short8_t b1 = *(const short8_t*)&lwt[(ct * 16 + l15) * 72 + 32 + q * 8];
    acc = __builtin_amdgcn_mfma_f32_16x16x32_bf16(a0, b0, acc, 0, 0, 0);
    acc = __builtin_amdgcn_mfma_f32_16x16x32_bf16(a1, b1, acc, 0, 0, 0);
    msgc[ct] = acc;
  }
  // combined = msg + inject -> back into X cols 64-127 (own strip rows only)
#pragma unroll
  for (int ct = 0; ct < 4; ++ct) {
    int col = ct * 16 + l15;
    float pj0 = sproj[col], pj1 = sproj[64 + col];
#pragma unroll
    for (int r = 0; r < 4; ++r) {
      int row = rowb + q * 4 + r;
      int ndl = row >> 1, b = row & 1;
      float inj = sfl[ndl] ? (b ? pj1 : pj0) : 0.f;
      lx[row * 136 + 64 + col] = (unsigned short)f2b(msgc[ct][r] + inj);
    }
  }

  // --- gate/cand phase: K=128 over [state | combined] ---
  short8_t xa[4];
#pragma unroll
  for (int ks = 0; ks < 4; ++ks)
    xa[ks] = *(const short8_t*)&lx[(rowb + l15) * 136 + ks * 32 + q * 8];
#pragma unroll
  for (int ct = 0; ct < 4; ++ct) {
    f32x4_t accg = {0.f, 0.f, 0.f, 0.f}, accc = {0.f, 0.f, 0.f, 0.f};
#pragma unroll
    for (int ks = 0; ks < 4; ++ks) {
      short8_t bg = *(const short8_t*)&lwt[4608 + (ct * 16 + l15) * 136 + ks * 32 + q * 8];
      short8_t bc = *(const short8_t*)&lwt[13312 + (ct * 16 + l15) * 136 + ks * 32 + q * 8];
      accg = __builtin_amdgcn_mfma_f32_16x16x32_bf16(xa[ks], bg, accg, 0, 0, 0);
      accc = __builtin_amdgcn_mfma_f32_16x16x32_bf16(xa[ks], bc, accc, 0, 0, 0);
    }
    int col = ct * 16 + l15;
    float bgv = sbias[col], bcv = sbias[64 + col];
#pragma unroll
    for (int rp = 0; rp < 2; ++rp) {
      int rowe = rowb + q * 4 + 2 * rp;      // even row; odd row = same node, batch1
      int nd = nd0 + (rowe >> 1);
      if (nd >= kN) continue;
      unsigned int pv = pk[nd * 64 + col];   // both batches' state, bf16
      float z0 = 1.f / (1.f + __expf(-(accg[2 * rp] + bgv)));
      float c0 = tanhf(accc[2 * rp] + bcv);
      stf(out, kOutOff + nd * 64 + col, (1.f - z0) * lo16(pv) + z0 * c0, f32);
      float z1 = 1.f / (1.f + __expf(-(accg[2 * rp + 1] + bgv)));
      float c1 = tanhf(accc[2 * rp + 1] + bcv);
      stf(out, kOutOff + kNH + nd * 64 + col, (1.f - z1) * hi16(pv) + z1 * c1, f32);
    }
  }
}

// --- readout: mean-pool efferent, tanh decode, policy heads -----------------
extern "C" __global__ void k_readout(const void* __restrict__ W_dec,
                                     const void* __restrict__ b_dec,
                                     const void* __restrict__ W_mean,
                                     const void* __restrict__ b_mean,
                                     const void* __restrict__ W_ls,
                                     const void* __restrict__ b_ls,
                                     const int* __restrict__ eff_idx,
                                     const int* __restrict__ dflag,
                                     void* __restrict__ out) {
  __shared__ float part[8][64];
  __shared__ float ro[128], dec[128];
  int f32 = dflag[0];
  int t = threadIdx.x;          // 512 threads = 8 waves
  int wv = t >> 6, lane = t & 63;
  int b = wv >> 2, g = wv & 3;  // wave -> (batch, quarter of eff list)
  float acc = 0.f;
#pragma unroll 4
  for (int i = 0; i < 64; ++i) {
    int n = eff_idx[g * 64 + i];
    acc += ldf(out, kOutOff + b * kNH + n * 64 + lane, f32);
  }
  part[wv][lane] = acc;
  __syncthreads();
  if (t < 128) {
    int bb = t >> 6, h = t & 63;
    float s = part[bb * 4 + 0][h] + part[bb * 4 + 1][h] +
              part[bb * 4 + 2][h] + part[bb * 4 + 3][h];
    ro[t] = s * (1.f / kEff);
  }
  __syncthreads();
  if (t < 128) {
    int bb = t >> 6, h = t & 63;
    float d = ldf(b_dec, h, f32);
    for (int k = 0; k < 64; ++k) d += ro[bb * 64 + k] * ldf(W_dec, k * 64 + h, f32);
    dec[t] = tanhf(d);
  }
  __syncthreads();
  if (t < kB * kA) {
    int bb = t / kA, a = t % kA;
    float m = ldf(b_mean, a, f32), l = ldf(b_ls, a, f32);
    for (int k = 0; k < 64; ++k) {
      float dv = dec[bb * 64 + k];
      m += dv * ldf(W_mean, k * kA + a, f32);
      l += dv * ldf(W_ls, k * kA + a, f32);
    }
    l = fminf(fmaxf(l, -5.f), 2.f);
    stf(out, t, m, f32);            // mean[2][18]
    stf(out, kB * kA + t, l, f32);  // log_std[2][18]
  }
}

extern "C" void kernel_launch(void* const* d_in, const int* in_sizes, int n_in,
                              void* d_out, int out_size, void* d_ws, size_t ws_size,
                              hipStream_t stream) {
  (void)in_sizes; (void)n_in; (void)out_size; (void)ws_size;
  const void* obs    = d_in[0];
  const void* state  = d_in[1];
  const void* W_in   = d_in[2];
  const void* b_in   = d_in[3];
  const void* W_msg  = d_in[4];
  const void* W_gate = d_in[5];
  const void* b_gate = d_in[6];
  const void* W_cand = d_in[7];
  const void* b_cand = d_in[8];
  const void* W_dec  = d_in[9];
  const void* b_dec  = d_in[10];
  const void* W_mean = d_in[11];
  const void* b_mean = d_in[12];
  const void* W_ls   = d_in[13];
  const void* b_ls   = d_in[14];
  const int* src = (const int*)d_in[15];
  const int* dst = (const int*)d_in[16];
  const int* aff = (const int*)d_in[17];
  const int* eff = (const int*)d_in[18];

  // workspace layout (~42 MB)
  int* wsp        = (int*)d_ws;
  int* flags      = wsp;                    // [N]     (memset 0)
  int* deg_c      = flags + kN;             // [kChunks*N]; becomes chunk_base in scan3
  int* row_off    = deg_c + kChunks * kN;   // [N+1] -> pad N+64
  int* partials   = row_off + (kN + 64);    // [512]
  int* dflag      = partials + 512;         // [16]
  float* projected = (float*)(dflag + 16);           // [128]
  int* sorted_src  = (int*)(projected + 128);        // [E]
  unsigned int* pk  = (unsigned int*)(sorted_src + kE);  // [N*H]
  unsigned int* agg = pk + kNH;                          // [N*H]
  unsigned short* wt = (unsigned short*)(agg + kNH);     // [20480] bf16

  hipMemsetAsync(flags, 0, size_t(kN) * sizeof(int), stream);  // flags only
  k_prep<<<1 + kHistB + kWprepBlocks, 1024, 0, stream>>>(
      (const unsigned short*)W_cand, obs, W_in, b_in, aff, dst,
      W_msg, W_gate, W_cand, dflag, flags, projected, deg_c, wt);
  k_scan1<<<kScanB, 256, 0, stream>>>(deg_c, row_off, partials);
  k_scan3<<<(kN + 255) / 256, 256, 0, stream>>>(row_off, partials, deg_c);
  k_scatter<<<kHistB + kPackBlocks, 1024, 0, stream>>>(
      src, dst, deg_c, sorted_src, (const unsigned short*)W_cand, state, pk);
  k_gather<<<(kN + 3) / 4, 256, 0, stream>>>(pk, row_off, sorted_src, agg);
  k_update<<<(kN + 31) / 32, 256, 0, stream>>>(pk, wt, b_gate, b_cand,
                                               agg, flags, projected, dflag, d_out);
  k_readout<<<1, 512, 0, stream>>>(W_dec, b_dec, W_mean, b_mean, W_ls, b_ls, eff,
                                   dflag, d_out);
}

// Round 7
// 281.069 us; speedup vs baseline: 1.2743x; 1.0157x over previous
//
#include <hip/hip_runtime.h>
#include <hip/hip_bf16.h>

// Problem constants (WholeBrainRateModel)
constexpr int kN   = 50000;    // nodes
constexpr int kH   = 64;       // hidden
constexpr int kB   = 2;        // batch
constexpr int kE   = 1000000;  // edges
constexpr int kObs = 128;
constexpr int kA   = 18;
constexpr int kAff = 512;
constexpr int kEff = 256;
constexpr int kNH  = kN * kH;
constexpr int kOutOff = 2 * kB * kA;  // 72 elements: mean+log_std before next_state
constexpr int kRanges = 8;                // node ranges (bid&7 -> XCD heuristic)
constexpr int kNr  = kN / kRanges;        // 6250 nodes per range (25 KB LDS)
constexpr int kChunks = 64;               // edge chunks
constexpr int kEc  = kE / kChunks;        // 15625 edges per chunk
constexpr int kHistB = kRanges * kChunks; // 512 hist/scatter blocks (1024 thr)
constexpr int kPackBlocks = (kNH + 8191) / 8192;  // 391 (8 elems/thread @1024)
constexpr int kWprepBlocks = 20;                  // 20480 / 1024
constexpr int kScanB = (kN + 255) / 256;          // 196 (1 node/thread)

typedef __attribute__((ext_vector_type(8))) short short8_t;  // 8 bf16 (4 VGPRs)
typedef __attribute__((ext_vector_type(4))) float f32x4_t;

// dtype-adaptive load/store (flag==1 -> float32 buffers, else bf16).
__device__ __forceinline__ float ldf(const void* p, int i, int f32) {
  if (f32) return ((const float*)p)[i];
  unsigned short u = ((const unsigned short*)p)[i];
  union { unsigned int x; float f; } v; v.x = ((unsigned int)u) << 16; return v.f;
}
__device__ __forceinline__ void stf(void* p, int i, float val, int f32) {
  if (f32) ((float*)p)[i] = val;
  else ((__hip_bfloat16*)p)[i] = __float2bfloat16(val);
}
__device__ __forceinline__ float lo16(unsigned int w) {
  union { unsigned int i; float f; } v; v.i = w << 16; return v.f;
}
__device__ __forceinline__ float hi16(unsigned int w) {
  union { unsigned int i; float f; } v; v.i = w & 0xffff0000u; return v.f;
}
__device__ __forceinline__ unsigned int f2b(float f) {  // rne bf16 bits
  union { float f; unsigned int u; } v; v.f = f;
  unsigned int r = v.u + 0x7fffu + ((v.u >> 16) & 1u);
  return r >> 16;
}
// wave-0 dtype detector (identical data in every block -> identical answer)
__device__ __forceinline__ int detect64(const unsigned short* wprobe, int t) {
  int hits = 0;
  for (int k = 0; k < 4; ++k) {
    unsigned short u = wprobe[(t * 4 + k) * 2];
    int e = (u >> 7) & 0xFF;
    if ((u & 0x7FFFu) != 0 && e >= 108 && e <= 128) hits++;
  }
  for (int off = 32; off; off >>= 1) hits += __shfl_down(hits, off);
  return (hits < 128) ? 1 : 0;  // few plausible-bf16 => f32
}

// --- fused prep (1024 thr): b0 = detect+flags+proj; b1..512 = hist; wprep ---
// Histogram with ZERO global atomics (rounds 3/4: every global atomic costs a
// ~32 B EA write packet; 1M of them = ~32 MB + 45+ us). Round 5 lesson: keep
// >=2 blk/CU and short per-thread loops. Block (r,c) LDS-counts chunk c's
// edges landing in range r, then plain coalesced stores to deg_c[c][range r].
// b0 also zeroes flags (only block that touches flags) -> no memset launch.
extern "C" __global__ __launch_bounds__(1024) void k_prep(
    const unsigned short* __restrict__ wprobe,
    const void* __restrict__ obs,
    const void* __restrict__ W_in,
    const void* __restrict__ b_in,
    const int* __restrict__ aff_idx,
    const int* __restrict__ dst,
    const void* __restrict__ W_msg,
    const void* __restrict__ W_gate,
    const void* __restrict__ W_cand,
    int* __restrict__ dflag,
    int* __restrict__ flags,
    float* __restrict__ projected,
    int* __restrict__ deg_c,
    unsigned short* __restrict__ wt) {
  __shared__ int sdeg[kNr];
  int t = threadIdx.x, b = blockIdx.x;
  if (b == 0) {
    __shared__ int sflag;
    if (t < 64) { int f = detect64(wprobe, t); if (t == 0) { sflag = f; dflag[0] = f; } }
    for (int i = t; i < kN; i += 1024) flags[i] = 0;
    __syncthreads();
    int f32 = sflag;
    if (t < kAff) flags[aff_idx[t]] = 1;
    if (t < kB * kH) {
      int bb = t >> 6, h = t & 63;
      float acc = ldf(b_in, h, f32);
      for (int o = 0; o < kObs; ++o)
        acc += ldf(obs, bb * kObs + o, f32) * ldf(W_in, o * kH + h, f32);
      projected[t] = acc;
    }
  } else if (b <= kHistB) {
    int h = b - 1, r = h & 7, c = h >> 3;
    int r0 = r * kNr;
    for (int i = t; i < kNr; i += 1024) sdeg[i] = 0;
    __syncthreads();
    int end = (c + 1) * kEc;
    for (int e = c * kEc + t; e < end; e += 1024) {
      unsigned rel = (unsigned)(dst[e] - r0);
      if (rel < (unsigned)kNr) atomicAdd(&sdeg[rel], 1);  // LDS atomic only
    }
    __syncthreads();
    for (int i = t; i < kNr; i += 1024) deg_c[c * kN + r0 + i] = sdeg[i];
  } else {
    __shared__ int sflag;
    if (t < 64) { int f = detect64(wprobe, t); if (t == 0) sflag = f; }
    __syncthreads();
    int f32 = sflag;
    int i = (b - 1 - kHistB) * 1024 + t;  // 0..20479
    if (i < 4096) {
      int n = i >> 6, k = i & 63;
      wt[i] = (unsigned short)f2b(ldf(W_msg, k * 64 + n, f32));
    } else if (i < 12288) {
      int j = i - 4096; int n = j >> 7, k = j & 127;
      wt[i] = (unsigned short)f2b(ldf(W_gate, k * 64 + n, f32));
    } else if (i < 20480) {
      int j = i - 12288; int n = j >> 7, k = j & 127;
      wt[i] = (unsigned short)f2b(ldf(W_cand, k * 64 + n, f32));
    }
  }
}

// --- scan: 196 blocks x 256 thr, 1 node/thread ------------------------------
extern "C" __global__ void k_scan1(const int* __restrict__ deg_c,
                                   int* __restrict__ row_off,
                                   int* __restrict__ partials) {
  __shared__ int sd[256];
  int t = threadIdx.x;
  int n = blockIdx.x * 256 + t;
  int s = 0;
  if (n < kN) {
    for (int c = 0; c < kChunks; ++c) s += deg_c[c * kN + n];
  }
  sd[t] = s;
  __syncthreads();
  for (int off = 1; off < 256; off <<= 1) {
    int v = (t >= off) ? sd[t - off] : 0;
    __syncthreads();
    sd[t] += v;
    __syncthreads();
  }
  int excl = sd[t] - s;
  if (t == 255) partials[blockIdx.x] = sd[255];
  if (n < kN) row_off[n] = excl;
}

// scan2 folded in; additionally transforms deg_c in place into
// chunk_base[c][n] = row_off[n] + sum_{c'<c} deg_c[c'][n]  (atomic-free
// scatter positions). Each node column is owned by exactly one thread.
extern "C" __global__ void k_scan3(int* __restrict__ row_off,
                                   const int* __restrict__ partials,
                                   int* __restrict__ deg_c) {
  __shared__ int sd[256];
  int t = threadIdx.x;
  int s = 0;
  for (int j = t; j < (int)blockIdx.x; j += 256) s += partials[j];
  sd[t] = s;
  __syncthreads();
  for (int off = 128; off; off >>= 1) {
    if (t < off) sd[t] += sd[t + off];
    __syncthreads();
  }
  int base = sd[0];
  int n = blockIdx.x * 256 + t;
  if (n < kN) {
    int v = row_off[n] + base;
    row_off[n] = v;
    int run = v;
#pragma unroll 8
    for (int c = 0; c < kChunks; ++c) {
      int d = deg_c[c * kN + n];
      deg_c[c * kN + n] = run;   // in-place: deg -> chunk_base
      run += d;
    }
  }
  if (blockIdx.x == 0 && t == 0) row_off[kN] = kE;
}

// --- scatter (+pack riding along), 1024 thr: ZERO global atomics ------------
// Block (r,c): load range r's chunk_base slice into an LDS cursor, then for
// chunk c's in-range edges take slots via LDS atomicAdd and store. Slots are
// disjoint across chunks by construction (chunk_base prefix). bid&7 = r keeps
// each range's ~500 KB sorted_src window written by one XCD (L2 locality).
// Pack blocks (bid >= 512): state -> bf16-packed pk, streaming BW filler.
extern "C" __global__ __launch_bounds__(1024) void k_scatter(
    const int* __restrict__ src,
    const int* __restrict__ dst,
    const int* __restrict__ chunk_base,
    int* __restrict__ sorted_src,
    const unsigned short* __restrict__ wprobe,
    const void* __restrict__ state,
    unsigned int* __restrict__ pack) {
  __shared__ int scur[kNr];
  int t = threadIdx.x;
  if (blockIdx.x < kHistB) {
    int r = blockIdx.x & 7, c = blockIdx.x >> 3;
    int r0 = r * kNr;
    for (int i = t; i < kNr; i += 1024) scur[i] = chunk_base[c * kN + r0 + i];
    __syncthreads();
    int end = (c + 1) * kEc;
    for (int e = c * kEc + t; e < end; e += 1024) {
      unsigned rel = (unsigned)(dst[e] - r0);
      if (rel < (unsigned)kNr) {
        int pos = atomicAdd(&scur[rel], 1);   // LDS atomic only
        sorted_src[pos] = src[e];
      }
    }
  } else {
    __shared__ int sflag;
    if (t < 64) { int f = detect64(wprobe, t); if (t == 0) sflag = f; }
    __syncthreads();
    int f32 = sflag;
    int i = (blockIdx.x - kHistB) * 8192 + t * 8;  // 8 elems/thread
    if (i < kNH) {
      uint4 o0, o1;
      if (!f32) {
        // bf16 inputs: pack is a pure bit-interleave (no rounding round-trip)
        uint4 a = *(const uint4*)((const unsigned short*)state + i);
        uint4 c4 = *(const uint4*)((const unsigned short*)state + kNH + i);
        o0.x = (a.x & 0xffffu) | (c4.x << 16);
        o0.y = (a.x >> 16)     | (c4.x & 0xffff0000u);
        o0.z = (a.y & 0xffffu) | (c4.y << 16);
        o0.w = (a.y >> 16)     | (c4.y & 0xffff0000u);
        o1.x = (a.z & 0xffffu) | (c4.z << 16);
        o1.y = (a.z >> 16)     | (c4.z & 0xffff0000u);
        o1.z = (a.w & 0xffffu) | (c4.w << 16);
        o1.w = (a.w >> 16)     | (c4.w & 0xffff0000u);
      } else {
        const float* sf = (const float*)state;
        unsigned int w[8];
#pragma unroll
        for (int k = 0; k < 8; ++k)
          w[k] = f2b(sf[i + k]) | (f2b(sf[kNH + i + k]) << 16);
        o0 = make_uint4(w[0], w[1], w[2], w[3]);
        o1 = make_uint4(w[4], w[5], w[6], w[7]);
      }
      *(uint4*)&pack[i] = o0;
      *(uint4*)&pack[i + 4] = o1;
    }
  }
}

// --- gather: one wave per node over its contiguous edge span ----------------
// 16-lane groups: group g handles edge e+g (and e+4+g), lane loads uint4
// (16 B = 4 packed h-columns). Cross-group shfl_xor(16/32) reduce at the end.
extern "C" __global__ __launch_bounds__(256) void k_gather(
    const unsigned int* __restrict__ pack,
    const int* __restrict__ row_off,     // span = [off[n], off[n+1])
    const int* __restrict__ sorted_src,
    unsigned int* __restrict__ agg) {
  int wave = threadIdx.x >> 6, lane = threadIdx.x & 63;
  int n = blockIdx.x * 4 + wave;
  if (n >= kN) return;
  int s  = row_off[n];
  int en = row_off[n + 1];
  int g = lane >> 4, col = lane & 15;
  const uint4* pk4 = (const uint4*)pack;
  float a0x = 0.f, a0y = 0.f, a0z = 0.f, a0w = 0.f;
  float a1x = 0.f, a1y = 0.f, a1z = 0.f, a1w = 0.f;
  for (int e = s; e < en; e += 8) {
#pragma unroll
    for (int h = 0; h < 2; ++h) {
      int ee = e + h * 4 + g;
      int idx = sorted_src[min(ee, en - 1)];
      uint4 wv = pk4[idx * 16 + col];
      if (ee >= en) { wv.x = 0u; wv.y = 0u; wv.z = 0u; wv.w = 0u; }
      a0x += lo16(wv.x); a1x += hi16(wv.x);
      a0y += lo16(wv.y); a1y += hi16(wv.y);
      a0z += lo16(wv.z); a1z += hi16(wv.z);
      a0w += lo16(wv.w); a1w += hi16(wv.w);
    }
  }
  // reduce the 4 edge-groups (lanes differing in bits 4,5) onto group 0
  a0x += __shfl_xor(a0x, 16); a0x += __shfl_xor(a0x, 32);
  a0y += __shfl_xor(a0y, 16); a0y += __shfl_xor(a0y, 32);
  a0z += __shfl_xor(a0z, 16); a0z += __shfl_xor(a0z, 32);
  a0w += __shfl_xor(a0w, 16); a0w += __shfl_xor(a0w, 32);
  a1x += __shfl_xor(a1x, 16); a1x += __shfl_xor(a1x, 32);
  a1y += __shfl_xor(a1y, 16); a1y += __shfl_xor(a1y, 32);
  a1z += __shfl_xor(a1z, 16); a1z += __shfl_xor(a1z, 32);
  a1w += __shfl_xor(a1w, 16); a1w += __shfl_xor(a1w, 32);
  if (g == 0) {
    uint4 o;
    o.x = f2b(a0x) | (f2b(a1x) << 16);
    o.y = f2b(a0y) | (f2b(a1y) << 16);
    o.z = f2b(a0z) | (f2b(a1z) << 16);
    o.w = f2b(a0w) | (f2b(a1w) << 16);
    ((uint4*)agg)[n * 16 + col] = o;
  }
}

// --- update (MFMA): msg = agg@W_msg (+inject), GRU gate/cand, next_state ----
// Block: 32 nodes x 2 batches = 64 M-rows. Wave w owns rows [16w,16w+16).
// X LDS [64][136]: cols 0-63 state bf16, cols 64-127 agg -> combined.
// MFMA B-fragments read DIRECTLY from global wt (40 KB, identical for all
// 1563 blocks -> L1/L2-resident). Round-6 change: dropping the 44 KB LDS
// weight stage lifts occupancy 2->8 blocks/CU (LDS 62->18.5 KB), trading
// cache-hit loads (latency-hidden at 16+ waves/CU) for the 25%-occupancy cap.
// A-frag: lane holds A[m=lane&15][k=(lane>>4)*8+j]; B-frag: B[k][n=lane&15];
// C: col=lane&15, row=(lane>>4)*4+reg (verified mappings, learn_hip m89/m91).
extern "C" __global__ __launch_bounds__(256) void k_update(
    const unsigned int* __restrict__ pk,
    const unsigned short* __restrict__ wt,   // prepped bf16 Wt msg|gate|cand
    const void* __restrict__ b_gate,
    const void* __restrict__ b_cand,
    const unsigned int* __restrict__ agg,
    const int* __restrict__ flags,
    const float* __restrict__ projected,
    const int* __restrict__ dflag,
    void* __restrict__ out) {
  __shared__ uint4 lx4[1088];    // 17408 B
  __shared__ float sbias[128];   // gate 0-63 | cand 64-127
  __shared__ float sproj[128];
  __shared__ int   sfl[32];
  unsigned short* lx  = (unsigned short*)lx4;
  int f32 = dflag[0];
  int t = threadIdx.x;
  int nd0 = blockIdx.x * 32;

  // X: uint4 loads from pk/agg, uint2 LDS writes (split batches to rows)
  const uint4* pk4 = (const uint4*)pk;
  const uint4* ag4 = (const uint4*)agg;
  for (int i = t; i < 512; i += 256) {
    int ndl = i >> 4, c4 = i & 15;
    int ndg = min(nd0 + ndl, kN - 1);
    uint4 pv = pk4[ndg * 16 + c4];
    uint4 av = ag4[ndg * 16 + c4];
    *(uint2*)&lx[(2 * ndl) * 136 + c4 * 4] =
        make_uint2((pv.x & 0xffffu) | (pv.y << 16), (pv.z & 0xffffu) | (pv.w << 16));
    *(uint2*)&lx[(2 * ndl + 1) * 136 + c4 * 4] =
        make_uint2((pv.x >> 16) | (pv.y & 0xffff0000u), (pv.z >> 16) | (pv.w & 0xffff0000u));
    *(uint2*)&lx[(2 * ndl) * 136 + 64 + c4 * 4] =
        make_uint2((av.x & 0xffffu) | (av.y << 16), (av.z & 0xffffu) | (av.w << 16));
    *(uint2*)&lx[(2 * ndl + 1) * 136 + 64 + c4 * 4] =
        make_uint2((av.x >> 16) | (av.y & 0xffff0000u), (av.z >> 16) | (av.w & 0xffff0000u));
  }
  if (t < 64) sbias[t] = ldf(b_gate, t, f32);
  else if (t < 128) sbias[t] = ldf(b_cand, t - 64, f32);
  else sproj[t - 128] = projected[t - 128];
  if (t < 32) sfl[t] = (nd0 + t < kN) ? flags[nd0 + t] : 0;
  __syncthreads();

  int w = t >> 6, lane = t & 63;
  int q = lane >> 4, l15 = lane & 15;
  int rowb = w * 16;
  const unsigned short* wm = wt;            // msg^T  [64 rows][64]  (row = out col)
  const unsigned short* wg = wt + 4096;     // gate^T [64 rows][128]
  const unsigned short* wc = wt + 12288;    // cand^T [64 rows][128]

  // --- msg phase: C[16x64] = agg[16x64] @ W_msg[64x64] ---
  short8_t a0 = *(const short8_t*)&lx[(rowb + l15) * 136 + 64 + q * 8];
  short8_t a1 = *(const short8_t*)&lx[(rowb + l15) * 136 + 96 + q * 8];
  f32x4_t msgc[4];
#pragma unroll
  for (int ct = 0; ct < 4; ++ct) {
    f32x4_t acc = {0.f, 0.f, 0.f, 0.f};
    short8_t b0 = *(const short8_t*)&wm[(ct * 16 + l15) * 64 + q * 8];
    short8_t b1 = *(const short8_t*)&wm[(ct * 16 + l15) * 64 + 32 + q * 8];
    acc = __builtin_amdgcn_mfma_f32_16x16x32_bf16(a0, b0, acc, 0, 0, 0);
    acc = __builtin_amdgcn_mfma_f32_16x16x32_bf16(a1, b1, acc, 0, 0, 0);
    msgc[ct] = acc;
  }
  // combined = msg + inject -> back into X cols 64-127 (own strip rows only)
#pragma unroll
  for (int ct = 0; ct < 4; ++ct) {
    int col = ct * 16 + l15;
    float pj0 = sproj[col], pj1 = sproj[64 + col];
#pragma unroll
    for (int r = 0; r < 4; ++r) {
      int row = rowb + q * 4 + r;
      int ndl = row >> 1, b = row & 1;
      float inj = sfl[ndl] ? (b ? pj1 : pj0) : 0.f;
      lx[row * 136 + 64 + col] = (unsigned short)f2b(msgc[ct][r] + inj);
    }
  }

  // --- gate/cand phase: K=128 over [state | combined] ---
  short8_t xa[4];
#pragma unroll
  for (int ks = 0; ks < 4; ++ks)
    xa[ks] = *(const short8_t*)&lx[(rowb + l15) * 136 + ks * 32 + q * 8];
#pragma unroll
  for (int ct = 0; ct < 4; ++ct) {
    f32x4_t accg = {0.f, 0.f, 0.f, 0.f}, accc = {0.f, 0.f, 0.f, 0.f};
#pragma unroll
    for (int ks = 0; ks < 4; ++ks) {
      short8_t bg = *(const short8_t*)&wg[(ct * 16 + l15) * 128 + ks * 32 + q * 8];
      short8_t bc = *(const short8_t*)&wc[(ct * 16 + l15) * 128 + ks * 32 + q * 8];
      accg = __builtin_amdgcn_mfma_f32_16x16x32_bf16(xa[ks], bg, accg, 0, 0, 0);
      accc = __builtin_amdgcn_mfma_f32_16x16x32_bf16(xa[ks], bc, accc, 0, 0, 0);
    }
    int col = ct * 16 + l15;
    float bgv = sbias[col], bcv = sbias[64 + col];
#pragma unroll
    for (int rp = 0; rp < 2; ++rp) {
      int rowe = rowb + q * 4 + 2 * rp;      // even row; odd row = same node, batch1
      int nd = nd0 + (rowe >> 1);
      if (nd >= kN) continue;
      unsigned int pv = pk[nd * 64 + col];   // both batches' state, bf16
      float z0 = 1.f / (1.f + __expf(-(accg[2 * rp] + bgv)));
      float c0 = tanhf(accc[2 * rp] + bcv);
      stf(out, kOutOff + nd * 64 + col, (1.f - z0) * lo16(pv) + z0 * c0, f32);
      float z1 = 1.f / (1.f + __expf(-(accg[2 * rp + 1] + bgv)));
      float c1 = tanhf(accc[2 * rp + 1] + bcv);
      stf(out, kOutOff + kNH + nd * 64 + col, (1.f - z1) * hi16(pv) + z1 * c1, f32);
    }
  }
}

// --- readout: mean-pool efferent, tanh decode, policy heads -----------------
extern "C" __global__ void k_readout(const void* __restrict__ W_dec,
                                     const void* __restrict__ b_dec,
                                     const void* __restrict__ W_mean,
                                     const void* __restrict__ b_mean,
                                     const void* __restrict__ W_ls,
                                     const void* __restrict__ b_ls,
                                     const int* __restrict__ eff_idx,
                                     const int* __restrict__ dflag,
                                     void* __restrict__ out) {
  __shared__ float part[8][64];
  __shared__ float ro[128], dec[128];
  int f32 = dflag[0];
  int t = threadIdx.x;          // 512 threads = 8 waves
  int wv = t >> 6, lane = t & 63;
  int b = wv >> 2, g = wv & 3;  // wave -> (batch, quarter of eff list)
  float acc = 0.f;
#pragma unroll 4
  for (int i = 0; i < 64; ++i) {
    int n = eff_idx[g * 64 + i];
    acc += ldf(out, kOutOff + b * kNH + n * 64 + lane, f32);
  }
  part[wv][lane] = acc;
  __syncthreads();
  if (t < 128) {
    int bb = t >> 6, h = t & 63;
    float s = part[bb * 4 + 0][h] + part[bb * 4 + 1][h] +
              part[bb * 4 + 2][h] + part[bb * 4 + 3][h];
    ro[t] = s * (1.f / kEff);
  }
  __syncthreads();
  if (t < 128) {
    int bb = t >> 6, h = t & 63;
    float d = ldf(b_dec, h, f32);
    for (int k = 0; k < 64; ++k) d += ro[bb * 64 + k] * ldf(W_dec, k * 64 + h, f32);
    dec[t] = tanhf(d);
  }
  __syncthreads();
  if (t < kB * kA) {
    int bb = t / kA, a = t % kA;
    float m = ldf(b_mean, a, f32), l = ldf(b_ls, a, f32);
    for (int k = 0; k < 64; ++k) {
      float dv = dec[bb * 64 + k];
      m += dv * ldf(W_mean, k * kA + a, f32);
      l += dv * ldf(W_ls, k * kA + a, f32);
    }
    l = fminf(fmaxf(l, -5.f), 2.f);
    stf(out, t, m, f32);            // mean[2][18]
    stf(out, kB * kA + t, l, f32);  // log_std[2][18]
  }
}

extern "C" void kernel_launch(void* const* d_in, const int* in_sizes, int n_in,
                              void* d_out, int out_size, void* d_ws, size_t ws_size,
                              hipStream_t stream) {
  (void)in_sizes; (void)n_in; (void)out_size; (void)ws_size;
  const void* obs    = d_in[0];
  const void* state  = d_in[1];
  const void* W_in   = d_in[2];
  const void* b_in   = d_in[3];
  const void* W_msg  = d_in[4];
  const void* W_gate = d_in[5];
  const void* b_gate = d_in[6];
  const void* W_cand = d_in[7];
  const void* b_cand = d_in[8];
  const void* W_dec  = d_in[9];
  const void* b_dec  = d_in[10];
  const void* W_mean = d_in[11];
  const void* b_mean = d_in[12];
  const void* W_ls   = d_in[13];
  const void* b_ls   = d_in[14];
  const int* src = (const int*)d_in[15];
  const int* dst = (const int*)d_in[16];
  const int* aff = (const int*)d_in[17];
  const int* eff = (const int*)d_in[18];

  // workspace layout (~42 MB)
  int* wsp        = (int*)d_ws;
  int* flags      = wsp;                    // [N]     (zeroed by k_prep b0)
  int* deg_c      = flags + kN;             // [kChunks*N]; becomes chunk_base in scan3
  int* row_off    = deg_c + kChunks * kN;   // [N+1] -> pad N+64
  int* partials   = row_off + (kN + 64);    // [512]
  int* dflag      = partials + 512;         // [16]
  float* projected = (float*)(dflag + 16);           // [128]
  int* sorted_src  = (int*)(projected + 128);        // [E]
  unsigned int* pk  = (unsigned int*)(sorted_src + kE);  // [N*H]
  unsigned int* agg = pk + kNH;                          // [N*H]
  unsigned short* wt = (unsigned short*)(agg + kNH);     // [20480] bf16

  k_prep<<<1 + kHistB + kWprepBlocks, 1024, 0, stream>>>(
      (const unsigned short*)W_cand, obs, W_in, b_in, aff, dst,
      W_msg, W_gate, W_cand, dflag, flags, projected, deg_c, wt);
  k_scan1<<<kScanB, 256, 0, stream>>>(deg_c, row_off, partials);
  k_scan3<<<kScanB, 256, 0, stream>>>(row_off, partials, deg_c);
  k_scatter<<<kHistB + kPackBlocks, 1024, 0, stream>>>(
      src, dst, deg_c, sorted_src, (const unsigned short*)W_cand, state, pk);
  k_gather<<<(kN + 3) / 4, 256, 0, stream>>>(pk, row_off, sorted_src, agg);
  k_update<<<(kN + 31) / 32, 256, 0, stream>>>(pk, wt, b_gate, b_cand,
                                               agg, flags, projected, dflag, d_out);
  k_readout<<<1, 512, 0, stream>>>(W_dec, b_dec, W_mean, b_mean, W_ls, b_ls, eff,
                                   dflag, d_out);
}